// Round 11
// baseline (261.618 us; speedup 1.0000x reference)
//
#include <hip/hip_runtime.h>

// GridGNN: 2x GCNConv(64->64) + ReLU, global_mean_pool, Linear(64->3), softmax.
// N=100000 nodes, E=1600000 edges, G=64 graphs, F=64 feats.
// R1: CSR + gather (no fp32 atomics). 2982 -> 454 us.
// R2: 4-B edge records, gemm2 folded past pooling. -> 393 us.
// R3: head folded; gemm+count fusion HURT. -> 332 us.
// R4: atomic-free CSR (LDS radix); bf16 feature rows. -> 235 us.
// R5: register-W GEMM. -> 199 us.
// R6: pool rebuilt; dinv prescaled into bf16 rows. -> 177 us.
// R7: own memset folded into k_hist. -> 172 us.
// R8: pool fused into gather2 + gcnt LDS-atomic bug -> 269 us (hist gated).
// R9: gcnt via bsearch in scanB (hist fixed) -> 190 us. gather_pool exposed
//     at 75us: block barrier after variable-degree loop (max-of-16 effect)
//     + latency-bound random row reads (FETCH 82MB at ~1.1TB/s, VALU 16%).
// R10: gather_pool reduce made wave-local (no __syncthreads; ballot+shfl_xor);
//      both gathers unrolled 8-wide for 2x memory-level parallelism.

typedef unsigned int u32;

#define NGRAPH 64
#define SCAN_T 256
#define SCAN_E 16
#define SCAN_B 4096
#define NB1 256  // blocks in hist/partition passes
#define GR 32    // rows per gemm tile (100000 % 32 == 0)

// ---- bf16 helpers (RN pack, exact unpack) ----
__device__ __forceinline__ float bflo(u32 v) { return __uint_as_float(v << 16); }
__device__ __forceinline__ float bfhi(u32 v) { return __uint_as_float(v & 0xffff0000u); }
__device__ __forceinline__ u32 packbf(float a, float b) {
    u32 ua = __float_as_uint(a); ua += 0x7fff + ((ua >> 16) & 1);
    u32 ub = __float_as_uint(b); ub += 0x7fff + ((ub >> 16) & 1);
    return (ua >> 16) | ((ub >> 16) << 16);
}

// ---- gemm: Out(bf16) = dinv[r] * (X @ W). Lane c holds W[:,c] in 64 VGPRs. ----
__global__ void k_gemm_reg(const float* __restrict__ X, const float* __restrict__ W,
                           const float* __restrict__ dinv, u32* __restrict__ Out,
                           int nRows) {
    __shared__ float xs[GR][64];
    int tid = threadIdx.x;      // 256
    int lane = tid & 63;        // output column
    int wv = tid >> 6;          // wave 0..3
    float wreg[64];
#pragma unroll
    for (int k = 0; k < 64; ++k) wreg[k] = W[k * 64 + lane];
    for (int t0 = blockIdx.x * GR; t0 < nRows; t0 += gridDim.x * GR) {
        __syncthreads();
        {
            const float4* X4 = (const float4*)(X + (size_t)t0 * 64);
            float4 v0 = X4[tid];
            float4 v1 = X4[tid + 256];
            ((float4*)&xs[0][0])[tid] = v0;
            ((float4*)&xs[0][0])[tid + 256] = v1;
        }
        __syncthreads();
#pragma unroll
        for (int rr = 0; rr < 8; rr += 4) {
            int r = wv * 8 + rr;
            float a0 = 0.f, a1 = 0.f, a2 = 0.f, a3 = 0.f;
#pragma unroll
            for (int k4 = 0; k4 < 16; ++k4) {
                float4 x0 = *(const float4*)&xs[r + 0][k4 * 4];
                float4 x1 = *(const float4*)&xs[r + 1][k4 * 4];
                float4 x2 = *(const float4*)&xs[r + 2][k4 * 4];
                float4 x3 = *(const float4*)&xs[r + 3][k4 * 4];
                a0 = fmaf(x0.x, wreg[k4 * 4 + 0], a0);
                a1 = fmaf(x1.x, wreg[k4 * 4 + 0], a1);
                a2 = fmaf(x2.x, wreg[k4 * 4 + 0], a2);
                a3 = fmaf(x3.x, wreg[k4 * 4 + 0], a3);
                a0 = fmaf(x0.y, wreg[k4 * 4 + 1], a0);
                a1 = fmaf(x1.y, wreg[k4 * 4 + 1], a1);
                a2 = fmaf(x2.y, wreg[k4 * 4 + 1], a2);
                a3 = fmaf(x3.y, wreg[k4 * 4 + 1], a3);
                a0 = fmaf(x0.z, wreg[k4 * 4 + 2], a0);
                a1 = fmaf(x1.z, wreg[k4 * 4 + 2], a1);
                a2 = fmaf(x2.z, wreg[k4 * 4 + 2], a2);
                a3 = fmaf(x3.z, wreg[k4 * 4 + 2], a3);
                a0 = fmaf(x0.w, wreg[k4 * 4 + 3], a0);
                a1 = fmaf(x1.w, wreg[k4 * 4 + 3], a1);
                a2 = fmaf(x2.w, wreg[k4 * 4 + 3], a2);
                a3 = fmaf(x3.w, wreg[k4 * 4 + 3], a3);
            }
            a0 *= dinv[t0 + r + 0];
            a1 *= dinv[t0 + r + 1];
            a2 *= dinv[t0 + r + 2];
            a3 *= dinv[t0 + r + 3];
            float o0 = __shfl_xor(a0, 1);
            float o1 = __shfl_xor(a1, 1);
            float o2 = __shfl_xor(a2, 1);
            float o3 = __shfl_xor(a3, 1);
            if (!(lane & 1)) {
                int h = lane >> 1;
                Out[(size_t)(t0 + r + 0) * 32 + h] = packbf(a0, o0);
                Out[(size_t)(t0 + r + 1) * 32 + h] = packbf(a1, o1);
                Out[(size_t)(t0 + r + 2) * 32 + h] = packbf(a2, o2);
                Out[(size_t)(t0 + r + 3) * 32 + h] = packbf(a3, o3);
            }
        }
    }
}

// ---- pass 1a: per-block LDS histogram over dst>>8; block 0 zeroes gsum ----
__global__ void k_hist(const int* __restrict__ dst, int* __restrict__ histT,
                       float* __restrict__ zbuf, int nZ, int nE, int NBUCK) {
    __shared__ int h[512];
    int tid = threadIdx.x;
    if (blockIdx.x == 0) {
        for (int i = tid; i < nZ; i += 256) zbuf[i] = 0.f;
    }
    for (int k = tid; k < NBUCK; k += 256) h[k] = 0;
    __syncthreads();
    int i = blockIdx.x * 256 + tid, stride = NB1 * 256;
    for (; i < nE; i += stride) atomicAdd(&h[dst[i] >> 8], 1);
    __syncthreads();
    for (int k = tid; k < NBUCK; k += 256) histT[k * NB1 + blockIdx.x] = h[k];
}

// ---- scan stage A ----
__global__ void k_scanA(const int* __restrict__ arr, int* __restrict__ outp,
                        int* __restrict__ bsums, int L) {
    __shared__ int sh[SCAN_T];
    int b = blockIdx.x, tid = threadIdx.x;
    int base = b * SCAN_B + tid * SCAN_E;
    int v[SCAN_E];
    int s = 0;
#pragma unroll
    for (int j = 0; j < SCAN_E; ++j) {
        int idx = base + j;
        int c = (idx < L) ? arr[idx] : 0;
        v[j] = s;
        s += c;
    }
    sh[tid] = s;
    __syncthreads();
    for (int off = 1; off < SCAN_T; off <<= 1) {
        int t = (tid >= off) ? sh[tid - off] : 0;
        __syncthreads();
        sh[tid] += t;
        __syncthreads();
    }
    int excl = (tid == 0) ? 0 : sh[tid - 1];
    if (tid == SCAN_T - 1) bsums[b] = sh[tid];
#pragma unroll
    for (int j = 0; j < SCAN_E; ++j) {
        int idx = base + j;
        if (idx < L) outp[idx] = excl + v[j];
    }
}

// ---- scan stage B (1 block, 512 thr): t0 serial scan; t1-3 bc fold;
//      t64-255 Wc fold; t256-319 gcnt via binary search on sorted batch ----
__global__ void k_scanB_fold(int* __restrict__ bsums, int nB,
                             const float* __restrict__ W2, const float* __restrict__ b2,
                             const float* __restrict__ Wl, const float* __restrict__ bl,
                             float* __restrict__ Wc, float* __restrict__ bc,
                             const int* __restrict__ batch, float* __restrict__ gcnt,
                             int nN) {
    int tid = threadIdx.x;
    if (tid == 0) {
        int run = 0;
        for (int i = 0; i < nB; ++i) {
            int t = bsums[i];
            bsums[i] = run;
            run += t;
        }
    } else if (tid >= 64 && tid < 64 + 192) {
        int i = tid - 64;
        int k = i / 3, j = i % 3;
        float acc = 0.f;
#pragma unroll
        for (int c = 0; c < 64; ++c) acc = fmaf(W2[k * 64 + c], Wl[c * 3 + j], acc);
        Wc[k * 3 + j] = acc;
    } else if (tid >= 1 && tid <= 3) {
        int j = tid - 1;
        float acc = bl[j];
#pragma unroll
        for (int c = 0; c < 64; ++c) acc = fmaf(b2[c], Wl[c * 3 + j], acc);
        bc[j] = acc;
    } else if (tid >= 256 && tid < 256 + NGRAPH) {
        int g = tid - 256;
        int lo = 0, hi = nN;
        while (lo < hi) { int mid = (lo + hi) >> 1; if (batch[mid] < g) lo = mid + 1; else hi = mid; }
        int lb = lo;
        lo = 0; hi = nN;
        int g1 = g + 1;
        while (lo < hi) { int mid = (lo + hi) >> 1; if (batch[mid] < g1) lo = mid + 1; else hi = mid; }
        gcnt[g] = (float)(lo - lb);
    }
}

// ---- pass 1c: partition edges into buckets via LDS cursors ----
__global__ void k_partition(const int* __restrict__ src, const int* __restrict__ dst,
                            const int* __restrict__ scanned, const int* __restrict__ bsums,
                            u32* __restrict__ staged, int nE, int NBUCK) {
    __shared__ int cur[512];
    int tid = threadIdx.x;
    for (int k = tid; k < NBUCK; k += 256) {
        int idx = k * NB1 + blockIdx.x;
        cur[k] = scanned[idx] + bsums[idx >> 12];
    }
    __syncthreads();
    int i = blockIdx.x * 256 + tid, stride = NB1 * 256;
    for (; i < nE; i += stride) {
        int d = dst[i];
        int k = d >> 8;
        int pos = atomicAdd(&cur[k], 1);
        staged[pos] = (u32)src[i] | ((u32)(d & 255) << 20);
    }
}

// ---- pass 2: per-bucket LDS count+scan+place -> esrc, rowptr, dinv ----
__global__ void k_pass2(const u32* __restrict__ staged, const int* __restrict__ scanned,
                        const int* __restrict__ bsums,
                        float* __restrict__ dinv, int* __restrict__ rowptr,
                        int* __restrict__ esrc, int nN, int nE, int NBUCK) {
    __shared__ int cnt[256], cur[256], sh[256];
    int bk = blockIdx.x, tid = threadIdx.x;
    int i0 = bk * NB1;
    int base = scanned[i0] + bsums[i0 >> 12];
    int end = nE;
    if (bk + 1 < NBUCK) {
        int i1 = (bk + 1) * NB1;
        end = scanned[i1] + bsums[i1 >> 12];
    }
    cnt[tid] = 0;
    __syncthreads();
    for (int e = base + tid; e < end; e += 256) atomicAdd(&cnt[staged[e] >> 20], 1);
    __syncthreads();
    int v = cnt[tid];
    sh[tid] = v;
    __syncthreads();
    for (int off = 1; off < 256; off <<= 1) {
        int t = (tid >= off) ? sh[tid - off] : 0;
        __syncthreads();
        sh[tid] += t;
        __syncthreads();
    }
    int excl = sh[tid] - v;
    int node = bk * 256 + tid;
    if (node < nN) {
        rowptr[node] = base + excl;
        dinv[node] = rsqrtf(1.0f + (float)v);
    }
    cur[tid] = excl;
    __syncthreads();
    for (int e = base + tid; e < end; e += 256) {
        u32 r = staged[e];
        int j = r >> 20;
        int pos = atomicAdd(&cur[j], 1);
        esrc[base + pos] = (int)(r & 0xFFFFFu);
    }
    if (bk == 0 && tid == 0) rowptr[nN] = nE;
}

// ---- 8-wide edge accumulation (independent loads first, then adds) ----
#define GACC8(H, lane, ep, acc) { \
    int s0 = (ep)[0], s1 = (ep)[1], s2 = (ep)[2], s3 = (ep)[3]; \
    int s4 = (ep)[4], s5 = (ep)[5], s6 = (ep)[6], s7 = (ep)[7]; \
    uint2 v0 = H[(size_t)s0 * 16 + lane]; uint2 v1 = H[(size_t)s1 * 16 + lane]; \
    uint2 v2 = H[(size_t)s2 * 16 + lane]; uint2 v3 = H[(size_t)s3 * 16 + lane]; \
    uint2 v4 = H[(size_t)s4 * 16 + lane]; uint2 v5 = H[(size_t)s5 * 16 + lane]; \
    uint2 v6 = H[(size_t)s6 * 16 + lane]; uint2 v7 = H[(size_t)s7 * 16 + lane]; \
    acc.x += bflo(v0.x); acc.y += bfhi(v0.x); acc.z += bflo(v0.y); acc.w += bfhi(v0.y); \
    acc.x += bflo(v1.x); acc.y += bfhi(v1.x); acc.z += bflo(v1.y); acc.w += bfhi(v1.y); \
    acc.x += bflo(v2.x); acc.y += bfhi(v2.x); acc.z += bflo(v2.y); acc.w += bfhi(v2.y); \
    acc.x += bflo(v3.x); acc.y += bfhi(v3.x); acc.z += bflo(v3.y); acc.w += bfhi(v3.y); \
    acc.x += bflo(v4.x); acc.y += bfhi(v4.x); acc.z += bflo(v4.y); acc.w += bfhi(v4.y); \
    acc.x += bflo(v5.x); acc.y += bfhi(v5.x); acc.z += bflo(v5.y); acc.w += bfhi(v5.y); \
    acc.x += bflo(v6.x); acc.y += bfhi(v6.x); acc.z += bflo(v6.y); acc.w += bfhi(v6.y); \
    acc.x += bflo(v7.x); acc.y += bfhi(v7.x); acc.z += bflo(v7.y); acc.w += bfhi(v7.y); }

#define GACC1(H, lane, s, acc) { \
    uint2 v = H[(size_t)(s) * 16 + lane]; \
    acc.x += bflo(v.x); acc.y += bfhi(v.x); acc.z += bflo(v.y); acc.w += bfhi(v.y); }

// ---- layer-1 gather: ys1 = dinv * relu(dinv*(sum hs + self) + b) -> bf16 ----
__global__ void k_gather_bf(const int* __restrict__ rowptr, const int* __restrict__ esrc,
                            const uint2* __restrict__ H, const float* __restrict__ dinv,
                            const float* __restrict__ bias, uint2* __restrict__ Obf,
                            int nN) {
    int node = blockIdx.x * 16 + (threadIdx.x >> 4);
    int lane = threadIdx.x & 15;
    if (node >= nN) return;
    int e0 = rowptr[node], e1 = rowptr[node + 1];
    float4 acc = make_float4(0.f, 0.f, 0.f, 0.f);
    int e = e0;
    for (; e + 7 < e1; e += 8) GACC8(H, lane, (esrc + e), acc)
    for (; e < e1; ++e) GACC1(H, lane, esrc[e], acc)
    float di = dinv[node];
    uint2 hv = H[(size_t)node * 16 + lane];
    float4 bb = ((const float4*)bias)[lane];
    float x0 = di * (acc.x + bflo(hv.x)) + bb.x;
    float x1 = di * (acc.y + bfhi(hv.x)) + bb.y;
    float x2 = di * (acc.z + bflo(hv.y)) + bb.z;
    float x3 = di * (acc.w + bfhi(hv.y)) + bb.w;
    x0 = fmaxf(x0, 0.f); x1 = fmaxf(x1, 0.f);
    x2 = fmaxf(x2, 0.f); x3 = fmaxf(x3, 0.f);
    Obf[(size_t)node * 16 + lane] =
        make_uint2(packbf(di * x0, di * x1), packbf(di * x2, di * x3));
}

// ---- layer-2 gather fused with pooling, wave-local reduce (no barriers) ----
__global__ void k_gather_pool(const int* __restrict__ rowptr, const int* __restrict__ esrc,
                              const uint2* __restrict__ H, const float* __restrict__ dinv,
                              const int* __restrict__ batch, float* __restrict__ gsum,
                              int nN) {
    int tid = threadIdx.x;
    int lane = tid & 15;
    int node = blockIdx.x * 16 + (tid >> 4);
    bool valid = node < nN;
    float4 z = make_float4(0.f, 0.f, 0.f, 0.f);
    int g = -1;
    if (valid) {
        g = batch[node];
        int e0 = rowptr[node], e1 = rowptr[node + 1];
        float4 acc = make_float4(0.f, 0.f, 0.f, 0.f);
        int e = e0;
        for (; e + 7 < e1; e += 8) GACC8(H, lane, (esrc + e), acc)
        for (; e < e1; ++e) GACC1(H, lane, esrc[e], acc)
        float di = dinv[node];
        uint2 hv = H[(size_t)node * 16 + lane];
        z.x = di * (acc.x + bflo(hv.x));
        z.y = di * (acc.y + bfhi(hv.x));
        z.z = di * (acc.z + bflo(hv.y));
        z.w = di * (acc.w + bfhi(hv.y));
    }
    // wave-local: do the 4 node-slots of this wave share one graph?
    int g0 = __shfl(g, 0);
    bool uni = (__ballot(valid && (g == g0)) == 0xFFFFFFFFFFFFFFFFULL);
    if (uni) {
        z.x += __shfl_xor(z.x, 16); z.y += __shfl_xor(z.y, 16);
        z.z += __shfl_xor(z.z, 16); z.w += __shfl_xor(z.w, 16);
        z.x += __shfl_xor(z.x, 32); z.y += __shfl_xor(z.y, 32);
        z.z += __shfl_xor(z.z, 32); z.w += __shfl_xor(z.w, 32);
        if ((tid & 63) < 16) {
            float* p = gsum + g0 * 64 + lane * 4;
            unsafeAtomicAdd(p + 0, z.x);
            unsafeAtomicAdd(p + 1, z.y);
            unsafeAtomicAdd(p + 2, z.z);
            unsafeAtomicAdd(p + 3, z.w);
        }
    } else if (valid) {
        float* p = gsum + g * 64 + lane * 4;
        unsafeAtomicAdd(p + 0, z.x);
        unsafeAtomicAdd(p + 1, z.y);
        unsafeAtomicAdd(p + 2, z.z);
        unsafeAtomicAdd(p + 3, z.w);
    }
}

// ---- head: out[g] = softmax( mean_g @ Wc + bc ), Wc [64x3] ----
__global__ void k_head(const float* __restrict__ gsum, const float* __restrict__ gcnt,
                       const float* __restrict__ Wc, const float* __restrict__ bc,
                       float* __restrict__ out) {
    int g = threadIdx.x;
    if (g >= NGRAPH) return;
    float inv = 1.0f / fmaxf(gcnt[g], 1.0f);
    float l0 = bc[0], l1 = bc[1], l2 = bc[2];
#pragma unroll
    for (int k = 0; k < 64; ++k) {
        float m = gsum[g * 64 + k] * inv;
        l0 = fmaf(m, Wc[k * 3 + 0], l0);
        l1 = fmaf(m, Wc[k * 3 + 1], l1);
        l2 = fmaf(m, Wc[k * 3 + 2], l2);
    }
    float mx = fmaxf(l0, fmaxf(l1, l2));
    float e0 = expf(l0 - mx), e1 = expf(l1 - mx), e2 = expf(l2 - mx);
    float s = e0 + e1 + e2;
    out[g * 3 + 0] = e0 / s;
    out[g * 3 + 1] = e1 / s;
    out[g * 3 + 2] = e2 / s;
}

extern "C" void kernel_launch(void* const* d_in, const int* in_sizes, int n_in,
                              void* d_out, int out_size, void* d_ws, size_t ws_size,
                              hipStream_t stream) {
    const float* x     = (const float*)d_in[0];
    const int*   ei    = (const int*)d_in[1];
    const int*   batch = (const int*)d_in[2];
    const float* W1    = (const float*)d_in[3];
    const float* b1    = (const float*)d_in[4];
    const float* W2    = (const float*)d_in[5];
    const float* b2    = (const float*)d_in[6];
    const float* Wl    = (const float*)d_in[7];
    const float* bl    = (const float*)d_in[8];
    float* out = (float*)d_out;

    int nN = in_sizes[2];
    int nE = in_sizes[1] / 2;
    const int* srcp = ei;
    const int* dstp = ei + nE;

    int NBUCK = (nN + 255) >> 8;          // 391
    int L = NBUCK * NB1;                   // 100096
    int nB = (L + SCAN_B - 1) / SCAN_B;    // 25

    char* ws = (char*)d_ws;
    size_t off = 0;
    auto alloc = [&](size_t bytes) -> void* {
        void* p = ws + off;
        off += (bytes + 255) & ~(size_t)255;
        return p;
    };
    float* dinv    = (float*)alloc((size_t)nN * 4);
    int*   rowptr  = (int*)alloc(((size_t)nN + 1) * 4);
    int*   hist    = (int*)alloc((size_t)L * 4);
    int*   scanned = (int*)alloc((size_t)L * 4);
    int*   bsums   = (int*)alloc(256 * 4);
    u32*   staged  = (u32*)alloc((size_t)nE * 4);
    int*   esrc    = (int*)alloc((size_t)nE * 4);
    u32*   Hbf     = (u32*)alloc((size_t)nN * 32 * 4);   // bf16-packed [nN][64]
    u32*   Ybf     = (u32*)alloc((size_t)nN * 32 * 4);
    float* gsum    = (float*)alloc(NGRAPH * 64 * 4);
    float* gcnt    = (float*)alloc(NGRAPH * 4);
    float* Wc      = (float*)alloc(64 * 3 * 4);
    float* bc      = (float*)alloc(3 * 4);

    // atomic-free CSR (block 0 zeroes gsum; gcnt set in scanB via bsearch)
    k_hist<<<NB1, 256, 0, stream>>>(dstp, hist, gsum, NGRAPH * 64, nE, NBUCK);
    k_scanA<<<nB, SCAN_T, 0, stream>>>(hist, scanned, bsums, L);
    k_scanB_fold<<<1, 512, 0, stream>>>(bsums, nB, W2, b2, Wl, bl, Wc, bc,
                                        batch, gcnt, nN);
    k_partition<<<NB1, 256, 0, stream>>>(srcp, dstp, scanned, bsums, staged, nE, NBUCK);
    k_pass2<<<NBUCK, 256, 0, stream>>>(staged, scanned, bsums, dinv, rowptr, esrc, nN, nE, NBUCK);

    // hs = dinv * (x@W1), bf16 rows
    k_gemm_reg<<<1024, 256, 0, stream>>>(x, W1, dinv, Hbf, nN);

    // layer 1: ys1 = dinv * relu(gather(hs)+b1) -> Ybf (bf16)
    k_gather_bf<<<(nN + 15) / 16, 256, 0, stream>>>(
        rowptr, esrc, (const uint2*)Hbf, dinv, b1, (uint2*)Ybf, nN);
    // layer 2 + pool fused (wave-local reduce): gsum[g] += dinv*(gather+self)
    k_gather_pool<<<(nN + 15) / 16, 256, 0, stream>>>(
        rowptr, esrc, (const uint2*)Ybf, dinv, batch, gsum, nN);

    // folded head
    k_head<<<1, 64, 0, stream>>>(gsum, gcnt, Wc, bc, out);
}

// Round 12
// 166.297 us; speedup vs baseline: 1.5732x; 1.5732x over previous
//
#include <hip/hip_runtime.h>

// GridGNN: 2x GCNConv(64->64) + ReLU, global_mean_pool, Linear(64->3), softmax.
// N=100000 nodes, E=1600000 edges, G=64 graphs, F=64 feats.
// R1: CSR + gather (no fp32 atomics). 2982 -> 454 us.
// R4: atomic-free CSR (LDS radix); bf16 feature rows. -> 235 us.
// R5: register-W GEMM. -> 199 us.  R6: pool rebuilt; dinv prescale. -> 177 us.
// R7: memset folded into k_hist. -> 172 us.   <-- best
// R8: gather2+pool fusion (block barrier) -> gather_pool 75us. 269 total (hist bug).
// R9: hist fixed -> 190. R10: wave-local reduce -> 1.6M contended gsum atomics,
//     gather_pool 150us, 262 total. LESSON: fusion loses both ways; the
//     barrier variant pays max-degree-of-16, the atomic variant pays 4x
//     contended atomics. Gathers are miss-queue x L3-latency bound (unroll
//     neutral). UNFUSE.
// R11: R7 topology restored + kept wins: bsearch gcnt in scanB, unroll-8
//      gathers, Z stored bf16 (pool reads halved).

typedef unsigned int u32;

#define NGRAPH 64
#define SCAN_T 256
#define SCAN_E 16
#define SCAN_B 4096
#define NB1 256  // blocks in hist/partition passes
#define GR 32    // rows per gemm tile (100000 % 32 == 0)

// ---- bf16 helpers (RN pack, exact unpack) ----
__device__ __forceinline__ float bflo(u32 v) { return __uint_as_float(v << 16); }
__device__ __forceinline__ float bfhi(u32 v) { return __uint_as_float(v & 0xffff0000u); }
__device__ __forceinline__ u32 packbf(float a, float b) {
    u32 ua = __float_as_uint(a); ua += 0x7fff + ((ua >> 16) & 1);
    u32 ub = __float_as_uint(b); ub += 0x7fff + ((ub >> 16) & 1);
    return (ua >> 16) | ((ub >> 16) << 16);
}

// ---- gemm: Out(bf16) = dinv[r] * (X @ W). Lane c holds W[:,c] in 64 VGPRs. ----
__global__ void k_gemm_reg(const float* __restrict__ X, const float* __restrict__ W,
                           const float* __restrict__ dinv, u32* __restrict__ Out,
                           int nRows) {
    __shared__ float xs[GR][64];
    int tid = threadIdx.x;      // 256
    int lane = tid & 63;        // output column
    int wv = tid >> 6;          // wave 0..3
    float wreg[64];
#pragma unroll
    for (int k = 0; k < 64; ++k) wreg[k] = W[k * 64 + lane];
    for (int t0 = blockIdx.x * GR; t0 < nRows; t0 += gridDim.x * GR) {
        __syncthreads();
        {
            const float4* X4 = (const float4*)(X + (size_t)t0 * 64);
            float4 v0 = X4[tid];
            float4 v1 = X4[tid + 256];
            ((float4*)&xs[0][0])[tid] = v0;
            ((float4*)&xs[0][0])[tid + 256] = v1;
        }
        __syncthreads();
#pragma unroll
        for (int rr = 0; rr < 8; rr += 4) {
            int r = wv * 8 + rr;
            float a0 = 0.f, a1 = 0.f, a2 = 0.f, a3 = 0.f;
#pragma unroll
            for (int k4 = 0; k4 < 16; ++k4) {
                float4 x0 = *(const float4*)&xs[r + 0][k4 * 4];
                float4 x1 = *(const float4*)&xs[r + 1][k4 * 4];
                float4 x2 = *(const float4*)&xs[r + 2][k4 * 4];
                float4 x3 = *(const float4*)&xs[r + 3][k4 * 4];
                a0 = fmaf(x0.x, wreg[k4 * 4 + 0], a0);
                a1 = fmaf(x1.x, wreg[k4 * 4 + 0], a1);
                a2 = fmaf(x2.x, wreg[k4 * 4 + 0], a2);
                a3 = fmaf(x3.x, wreg[k4 * 4 + 0], a3);
                a0 = fmaf(x0.y, wreg[k4 * 4 + 1], a0);
                a1 = fmaf(x1.y, wreg[k4 * 4 + 1], a1);
                a2 = fmaf(x2.y, wreg[k4 * 4 + 1], a2);
                a3 = fmaf(x3.y, wreg[k4 * 4 + 1], a3);
                a0 = fmaf(x0.z, wreg[k4 * 4 + 2], a0);
                a1 = fmaf(x1.z, wreg[k4 * 4 + 2], a1);
                a2 = fmaf(x2.z, wreg[k4 * 4 + 2], a2);
                a3 = fmaf(x3.z, wreg[k4 * 4 + 2], a3);
                a0 = fmaf(x0.w, wreg[k4 * 4 + 3], a0);
                a1 = fmaf(x1.w, wreg[k4 * 4 + 3], a1);
                a2 = fmaf(x2.w, wreg[k4 * 4 + 3], a2);
                a3 = fmaf(x3.w, wreg[k4 * 4 + 3], a3);
            }
            a0 *= dinv[t0 + r + 0];
            a1 *= dinv[t0 + r + 1];
            a2 *= dinv[t0 + r + 2];
            a3 *= dinv[t0 + r + 3];
            float o0 = __shfl_xor(a0, 1);
            float o1 = __shfl_xor(a1, 1);
            float o2 = __shfl_xor(a2, 1);
            float o3 = __shfl_xor(a3, 1);
            if (!(lane & 1)) {
                int h = lane >> 1;
                Out[(size_t)(t0 + r + 0) * 32 + h] = packbf(a0, o0);
                Out[(size_t)(t0 + r + 1) * 32 + h] = packbf(a1, o1);
                Out[(size_t)(t0 + r + 2) * 32 + h] = packbf(a2, o2);
                Out[(size_t)(t0 + r + 3) * 32 + h] = packbf(a3, o3);
            }
        }
    }
}

// ---- pass 1a: per-block LDS histogram over dst>>8; block 0 zeroes gsum ----
__global__ void k_hist(const int* __restrict__ dst, int* __restrict__ histT,
                       float* __restrict__ zbuf, int nZ, int nE, int NBUCK) {
    __shared__ int h[512];
    int tid = threadIdx.x;
    if (blockIdx.x == 0) {
        for (int i = tid; i < nZ; i += 256) zbuf[i] = 0.f;
    }
    for (int k = tid; k < NBUCK; k += 256) h[k] = 0;
    __syncthreads();
    int i = blockIdx.x * 256 + tid, stride = NB1 * 256;
    for (; i < nE; i += stride) atomicAdd(&h[dst[i] >> 8], 1);
    __syncthreads();
    for (int k = tid; k < NBUCK; k += 256) histT[k * NB1 + blockIdx.x] = h[k];
}

// ---- scan stage A ----
__global__ void k_scanA(const int* __restrict__ arr, int* __restrict__ outp,
                        int* __restrict__ bsums, int L) {
    __shared__ int sh[SCAN_T];
    int b = blockIdx.x, tid = threadIdx.x;
    int base = b * SCAN_B + tid * SCAN_E;
    int v[SCAN_E];
    int s = 0;
#pragma unroll
    for (int j = 0; j < SCAN_E; ++j) {
        int idx = base + j;
        int c = (idx < L) ? arr[idx] : 0;
        v[j] = s;
        s += c;
    }
    sh[tid] = s;
    __syncthreads();
    for (int off = 1; off < SCAN_T; off <<= 1) {
        int t = (tid >= off) ? sh[tid - off] : 0;
        __syncthreads();
        sh[tid] += t;
        __syncthreads();
    }
    int excl = (tid == 0) ? 0 : sh[tid - 1];
    if (tid == SCAN_T - 1) bsums[b] = sh[tid];
#pragma unroll
    for (int j = 0; j < SCAN_E; ++j) {
        int idx = base + j;
        if (idx < L) outp[idx] = excl + v[j];
    }
}

// ---- scan stage B (1 block, 512 thr): t0 serial scan; t1-3 bc fold;
//      t64-255 Wc fold; t256-319 gcnt via binary search on sorted batch ----
__global__ void k_scanB_fold(int* __restrict__ bsums, int nB,
                             const float* __restrict__ W2, const float* __restrict__ b2,
                             const float* __restrict__ Wl, const float* __restrict__ bl,
                             float* __restrict__ Wc, float* __restrict__ bc,
                             const int* __restrict__ batch, float* __restrict__ gcnt,
                             int nN) {
    int tid = threadIdx.x;
    if (tid == 0) {
        int run = 0;
        for (int i = 0; i < nB; ++i) {
            int t = bsums[i];
            bsums[i] = run;
            run += t;
        }
    } else if (tid >= 64 && tid < 64 + 192) {
        int i = tid - 64;
        int k = i / 3, j = i % 3;
        float acc = 0.f;
#pragma unroll
        for (int c = 0; c < 64; ++c) acc = fmaf(W2[k * 64 + c], Wl[c * 3 + j], acc);
        Wc[k * 3 + j] = acc;
    } else if (tid >= 1 && tid <= 3) {
        int j = tid - 1;
        float acc = bl[j];
#pragma unroll
        for (int c = 0; c < 64; ++c) acc = fmaf(b2[c], Wl[c * 3 + j], acc);
        bc[j] = acc;
    } else if (tid >= 256 && tid < 256 + NGRAPH) {
        int g = tid - 256;
        int lo = 0, hi = nN;
        while (lo < hi) { int mid = (lo + hi) >> 1; if (batch[mid] < g) lo = mid + 1; else hi = mid; }
        int lb = lo;
        lo = 0; hi = nN;
        int g1 = g + 1;
        while (lo < hi) { int mid = (lo + hi) >> 1; if (batch[mid] < g1) lo = mid + 1; else hi = mid; }
        gcnt[g] = (float)(lo - lb);
    }
}

// ---- pass 1c: partition edges into buckets via LDS cursors ----
__global__ void k_partition(const int* __restrict__ src, const int* __restrict__ dst,
                            const int* __restrict__ scanned, const int* __restrict__ bsums,
                            u32* __restrict__ staged, int nE, int NBUCK) {
    __shared__ int cur[512];
    int tid = threadIdx.x;
    for (int k = tid; k < NBUCK; k += 256) {
        int idx = k * NB1 + blockIdx.x;
        cur[k] = scanned[idx] + bsums[idx >> 12];
    }
    __syncthreads();
    int i = blockIdx.x * 256 + tid, stride = NB1 * 256;
    for (; i < nE; i += stride) {
        int d = dst[i];
        int k = d >> 8;
        int pos = atomicAdd(&cur[k], 1);
        staged[pos] = (u32)src[i] | ((u32)(d & 255) << 20);
    }
}

// ---- pass 2: per-bucket LDS count+scan+place -> esrc, rowptr, dinv ----
__global__ void k_pass2(const u32* __restrict__ staged, const int* __restrict__ scanned,
                        const int* __restrict__ bsums,
                        float* __restrict__ dinv, int* __restrict__ rowptr,
                        int* __restrict__ esrc, int nN, int nE, int NBUCK) {
    __shared__ int cnt[256], cur[256], sh[256];
    int bk = blockIdx.x, tid = threadIdx.x;
    int i0 = bk * NB1;
    int base = scanned[i0] + bsums[i0 >> 12];
    int end = nE;
    if (bk + 1 < NBUCK) {
        int i1 = (bk + 1) * NB1;
        end = scanned[i1] + bsums[i1 >> 12];
    }
    cnt[tid] = 0;
    __syncthreads();
    for (int e = base + tid; e < end; e += 256) atomicAdd(&cnt[staged[e] >> 20], 1);
    __syncthreads();
    int v = cnt[tid];
    sh[tid] = v;
    __syncthreads();
    for (int off = 1; off < 256; off <<= 1) {
        int t = (tid >= off) ? sh[tid - off] : 0;
        __syncthreads();
        sh[tid] += t;
        __syncthreads();
    }
    int excl = sh[tid] - v;
    int node = bk * 256 + tid;
    if (node < nN) {
        rowptr[node] = base + excl;
        dinv[node] = rsqrtf(1.0f + (float)v);
    }
    cur[tid] = excl;
    __syncthreads();
    for (int e = base + tid; e < end; e += 256) {
        u32 r = staged[e];
        int j = r >> 20;
        int pos = atomicAdd(&cur[j], 1);
        esrc[base + pos] = (int)(r & 0xFFFFFu);
    }
    if (bk == 0 && tid == 0) rowptr[nN] = nE;
}

// ---- 8-wide edge accumulation (independent loads first, then adds) ----
#define GACC8(H, lane, ep, acc) { \
    int s0 = (ep)[0], s1 = (ep)[1], s2 = (ep)[2], s3 = (ep)[3]; \
    int s4 = (ep)[4], s5 = (ep)[5], s6 = (ep)[6], s7 = (ep)[7]; \
    uint2 v0 = H[(size_t)s0 * 16 + lane]; uint2 v1 = H[(size_t)s1 * 16 + lane]; \
    uint2 v2 = H[(size_t)s2 * 16 + lane]; uint2 v3 = H[(size_t)s3 * 16 + lane]; \
    uint2 v4 = H[(size_t)s4 * 16 + lane]; uint2 v5 = H[(size_t)s5 * 16 + lane]; \
    uint2 v6 = H[(size_t)s6 * 16 + lane]; uint2 v7 = H[(size_t)s7 * 16 + lane]; \
    acc.x += bflo(v0.x); acc.y += bfhi(v0.x); acc.z += bflo(v0.y); acc.w += bfhi(v0.y); \
    acc.x += bflo(v1.x); acc.y += bfhi(v1.x); acc.z += bflo(v1.y); acc.w += bfhi(v1.y); \
    acc.x += bflo(v2.x); acc.y += bfhi(v2.x); acc.z += bflo(v2.y); acc.w += bfhi(v2.y); \
    acc.x += bflo(v3.x); acc.y += bfhi(v3.x); acc.z += bflo(v3.y); acc.w += bfhi(v3.y); \
    acc.x += bflo(v4.x); acc.y += bfhi(v4.x); acc.z += bflo(v4.y); acc.w += bfhi(v4.y); \
    acc.x += bflo(v5.x); acc.y += bfhi(v5.x); acc.z += bflo(v5.y); acc.w += bfhi(v5.y); \
    acc.x += bflo(v6.x); acc.y += bfhi(v6.x); acc.z += bflo(v6.y); acc.w += bfhi(v6.y); \
    acc.x += bflo(v7.x); acc.y += bfhi(v7.x); acc.z += bflo(v7.y); acc.w += bfhi(v7.y); }

#define GACC1(H, lane, s, acc) { \
    uint2 v = H[(size_t)(s) * 16 + lane]; \
    acc.x += bflo(v.x); acc.y += bfhi(v.x); acc.z += bflo(v.y); acc.w += bfhi(v.y); }

// ---- gather (bf16 rows): x = dinv[d]*(sum + self); optional bias/relu;
//      store bf16: outscale ? dinv*x : x ----
__global__ void k_gather_bf(const int* __restrict__ rowptr, const int* __restrict__ esrc,
                            const uint2* __restrict__ H, const float* __restrict__ dinv,
                            const float* __restrict__ bias, uint2* __restrict__ Obf,
                            int nN, int relu, int addb, int outscale) {
    int node = blockIdx.x * 16 + (threadIdx.x >> 4);
    int lane = threadIdx.x & 15;
    if (node >= nN) return;
    int e0 = rowptr[node], e1 = rowptr[node + 1];
    float4 acc = make_float4(0.f, 0.f, 0.f, 0.f);
    int e = e0;
    for (; e + 7 < e1; e += 8) GACC8(H, lane, (esrc + e), acc)
    for (; e < e1; ++e) GACC1(H, lane, esrc[e], acc)
    float di = dinv[node];
    uint2 hv = H[(size_t)node * 16 + lane];
    float x0 = di * (acc.x + bflo(hv.x));
    float x1 = di * (acc.y + bfhi(hv.x));
    float x2 = di * (acc.z + bflo(hv.y));
    float x3 = di * (acc.w + bfhi(hv.y));
    if (addb) {
        float4 bb = ((const float4*)bias)[lane];
        x0 += bb.x; x1 += bb.y; x2 += bb.z; x3 += bb.w;
    }
    if (relu) {
        x0 = fmaxf(x0, 0.f); x1 = fmaxf(x1, 0.f);
        x2 = fmaxf(x2, 0.f); x3 = fmaxf(x3, 0.f);
    }
    float sc = outscale ? di : 1.0f;
    Obf[(size_t)node * 16 + lane] =
        make_uint2(packbf(sc * x0, sc * x1), packbf(sc * x2, sc * x3));
}

// ---- pool (bf16 Z): CH=64 nodes/block; uniform-chunk fast path ----
__global__ void k_pool(const u32* __restrict__ Z32, const int* __restrict__ batch,
                       float* __restrict__ gsum, int nN) {
    const int CH = 64;
    __shared__ int bsh[CH];
    __shared__ float red[4][64];
    int n0 = blockIdx.x * CH;
    int tid = threadIdx.x;
    int f = tid & 63, rl = tid >> 6;
    int nend = n0 + CH; if (nend > nN) nend = nN;
    int cnt = nend - n0;
    if (cnt <= 0) return;
    if (tid < CH) bsh[tid] = (n0 + tid < nN) ? batch[n0 + tid] : -1;
    __syncthreads();
    int g0 = bsh[0];
    bool uniform = (cnt == CH) && (bsh[CH - 1] == g0);
    int col = f >> 1, half = f & 1;
    if (uniform) {
        const u32* Zp = Z32 + (size_t)n0 * 32 + col;
        float acc = 0.f;
#pragma unroll
        for (int r = 0; r < 16; ++r) {
            u32 v = Zp[(size_t)(rl + r * 4) * 32];
            acc += half ? bfhi(v) : bflo(v);
        }
        red[rl][f] = acc;
        __syncthreads();
        if (rl == 0) {
            float s = red[0][f] + red[1][f] + red[2][f] + red[3][f];
            unsafeAtomicAdd(&gsum[g0 * 64 + f], s);
        }
    } else {
        int curg = -1; float acc = 0.f;
        for (int n = n0 + rl; n < nend; n += 4) {
            int g = bsh[n - n0];
            if (g != curg) {
                if (curg >= 0) unsafeAtomicAdd(&gsum[curg * 64 + f], acc);
                curg = g; acc = 0.f;
            }
            u32 v = Z32[(size_t)n * 32 + col];
            acc += half ? bfhi(v) : bflo(v);
        }
        if (curg >= 0) unsafeAtomicAdd(&gsum[curg * 64 + f], acc);
    }
}

// ---- head: out[g] = softmax( mean_g @ Wc + bc ), Wc [64x3] ----
__global__ void k_head(const float* __restrict__ gsum, const float* __restrict__ gcnt,
                       const float* __restrict__ Wc, const float* __restrict__ bc,
                       float* __restrict__ out) {
    int g = threadIdx.x;
    if (g >= NGRAPH) return;
    float inv = 1.0f / fmaxf(gcnt[g], 1.0f);
    float l0 = bc[0], l1 = bc[1], l2 = bc[2];
#pragma unroll
    for (int k = 0; k < 64; ++k) {
        float m = gsum[g * 64 + k] * inv;
        l0 = fmaf(m, Wc[k * 3 + 0], l0);
        l1 = fmaf(m, Wc[k * 3 + 1], l1);
        l2 = fmaf(m, Wc[k * 3 + 2], l2);
    }
    float mx = fmaxf(l0, fmaxf(l1, l2));
    float e0 = expf(l0 - mx), e1 = expf(l1 - mx), e2 = expf(l2 - mx);
    float s = e0 + e1 + e2;
    out[g * 3 + 0] = e0 / s;
    out[g * 3 + 1] = e1 / s;
    out[g * 3 + 2] = e2 / s;
}

extern "C" void kernel_launch(void* const* d_in, const int* in_sizes, int n_in,
                              void* d_out, int out_size, void* d_ws, size_t ws_size,
                              hipStream_t stream) {
    const float* x     = (const float*)d_in[0];
    const int*   ei    = (const int*)d_in[1];
    const int*   batch = (const int*)d_in[2];
    const float* W1    = (const float*)d_in[3];
    const float* b1    = (const float*)d_in[4];
    const float* W2    = (const float*)d_in[5];
    const float* b2    = (const float*)d_in[6];
    const float* Wl    = (const float*)d_in[7];
    const float* bl    = (const float*)d_in[8];
    float* out = (float*)d_out;

    int nN = in_sizes[2];
    int nE = in_sizes[1] / 2;
    const int* srcp = ei;
    const int* dstp = ei + nE;

    int NBUCK = (nN + 255) >> 8;          // 391
    int L = NBUCK * NB1;                   // 100096
    int nB = (L + SCAN_B - 1) / SCAN_B;    // 25

    char* ws = (char*)d_ws;
    size_t off = 0;
    auto alloc = [&](size_t bytes) -> void* {
        void* p = ws + off;
        off += (bytes + 255) & ~(size_t)255;
        return p;
    };
    float* dinv    = (float*)alloc((size_t)nN * 4);
    int*   rowptr  = (int*)alloc(((size_t)nN + 1) * 4);
    int*   hist    = (int*)alloc((size_t)L * 4);
    int*   scanned = (int*)alloc((size_t)L * 4);
    int*   bsums   = (int*)alloc(256 * 4);
    u32*   staged  = (u32*)alloc((size_t)nE * 4);
    int*   esrc    = (int*)alloc((size_t)nE * 4);
    u32*   Hbf     = (u32*)alloc((size_t)nN * 32 * 4);   // bf16-packed [nN][64]
    u32*   Ybf     = (u32*)alloc((size_t)nN * 32 * 4);
    u32*   Zbf     = (u32*)alloc((size_t)nN * 32 * 4);
    float* gsum    = (float*)alloc(NGRAPH * 64 * 4);
    float* gcnt    = (float*)alloc(NGRAPH * 4);
    float* Wc      = (float*)alloc(64 * 3 * 4);
    float* bc      = (float*)alloc(3 * 4);

    // atomic-free CSR (block 0 zeroes gsum; gcnt set in scanB via bsearch)
    k_hist<<<NB1, 256, 0, stream>>>(dstp, hist, gsum, NGRAPH * 64, nE, NBUCK);
    k_scanA<<<nB, SCAN_T, 0, stream>>>(hist, scanned, bsums, L);
    k_scanB_fold<<<1, 512, 0, stream>>>(bsums, nB, W2, b2, Wl, bl, Wc, bc,
                                        batch, gcnt, nN);
    k_partition<<<NB1, 256, 0, stream>>>(srcp, dstp, scanned, bsums, staged, nE, NBUCK);
    k_pass2<<<NBUCK, 256, 0, stream>>>(staged, scanned, bsums, dinv, rowptr, esrc, nN, nE, NBUCK);

    // hs = dinv * (x@W1), bf16 rows
    k_gemm_reg<<<1024, 256, 0, stream>>>(x, W1, dinv, Hbf, nN);

    // layer 1: ys1 = dinv * relu(gather(hs)+b1) -> Ybf
    k_gather_bf<<<(nN + 15) / 16, 256, 0, stream>>>(
        rowptr, esrc, (const uint2*)Hbf, dinv, b1, (uint2*)Ybf, nN, 1, 1, 1);
    // layer 2: z = dinv*(gather(ys1)+self) -> Zbf (bf16, no extra scale)
    k_gather_bf<<<(nN + 15) / 16, 256, 0, stream>>>(
        rowptr, esrc, (const uint2*)Ybf, dinv, nullptr, (uint2*)Zbf, nN, 0, 0, 0);

    // pool Zbf + folded head
    k_pool<<<(nN + 63) / 64, 256, 0, stream>>>(Zbf, batch, gsum, nN);
    k_head<<<1, 64, 0, stream>>>(gsum, gcnt, Wc, bc, out);
}

// Round 13
// 155.437 us; speedup vs baseline: 1.6831x; 1.0699x over previous
//
#include <hip/hip_runtime.h>

// GridGNN: 2x GCNConv(64->64) + ReLU, global_mean_pool, Linear(64->3), softmax.
// N=100000 nodes, E=1600000 edges, G=64 graphs, F=64 feats.
// R1 CSR+gather 454 | R4 radix CSR + bf16 rows 235 | R5 reg-GEMM 199
// R6 pool+prescale 177 | R7 memset fold 172 | R8-R10 fusion detours (269/190/262)
// R11 unfused best-of 166.  LESSON: gathers are the floor (~70us, random
// 128B rows, ~5.8TB/s effective); fusion into them always lost.
// R12: fp8(e4m3, OCP) feature rows for both gathers -> row = 64B = 1 cache
//      line (was 2). HW cvt_pk converters; fp32 accumulation; Z/pool stay
//      bf16. Predicted absmax ~4e-4 (threshold 7.2e-3).

typedef unsigned int u32;
typedef float v2f __attribute__((ext_vector_type(2)));

#define NGRAPH 64
#define SCAN_T 256
#define SCAN_E 16
#define SCAN_B 4096
#define NB1 256
#define GR 32

#if __has_builtin(__builtin_amdgcn_cvt_pk_f32_fp8) && __has_builtin(__builtin_amdgcn_cvt_pk_fp8_f32)
#define HAVE_FP8_CVT 1
#endif

// ---- bf16 helpers ----
__device__ __forceinline__ float bflo(u32 v) { return __uint_as_float(v << 16); }
__device__ __forceinline__ float bfhi(u32 v) { return __uint_as_float(v & 0xffff0000u); }
__device__ __forceinline__ u32 packbf(float a, float b) {
    u32 ua = __float_as_uint(a); ua += 0x7fff + ((ua >> 16) & 1);
    u32 ub = __float_as_uint(b); ub += 0x7fff + ((ub >> 16) & 1);
    return (ua >> 16) | ((ub >> 16) << 16);
}

// ---- fp8 e4m3 (OCP) helpers ----
#ifndef HAVE_FP8_CVT
__device__ __forceinline__ float fp8_to_f32(u32 b) {
    u32 s = b & 0x80;
    u32 em = b & 0x7f;
    float fn = __uint_as_float((em << 20) + 0x3C000000u);   // normals: 2^(e-7)*(1+m/8)
    float fs = (float)(b & 7) * 0.001953125f;               // subnormals: m*2^-9
    float f = (em & 0x78) ? fn : fs;
    return s ? -f : f;
}
__device__ __forceinline__ u32 f32_to_fp8(float f) {
    u32 u = __float_as_uint(f);
    u32 s = (u >> 24) & 0x80;
    u32 a = u & 0x7fffffff;
    float af = __uint_as_float(a);
    if (af < 0.015625f) {                    // subnormal/zero
        u32 m = (u32)__float2int_rn(af * 512.0f);
        if (m >= 8) return s | 0x08;
        return s | m;
    }
    u32 r = a + 0x0007FFFFu + ((a >> 20) & 1);  // RNE at bit 20
    int em = (int)(r >> 20) - (120 << 3);
    if (em > 0x7E) em = 0x7E;                    // clamp to 448
    if (em < 0) em = 0;
    return s | (u32)em;
}
#endif

__device__ __forceinline__ void up_add(u32 v, float4& acc) {
#ifdef HAVE_FP8_CVT
    v2f lo = __builtin_amdgcn_cvt_pk_f32_fp8((int)v, false);
    v2f hi = __builtin_amdgcn_cvt_pk_f32_fp8((int)v, true);
    acc.x += lo.x; acc.y += lo.y; acc.z += hi.x; acc.w += hi.y;
#else
    acc.x += fp8_to_f32(v & 255);         acc.y += fp8_to_f32((v >> 8) & 255);
    acc.z += fp8_to_f32((v >> 16) & 255); acc.w += fp8_to_f32((v >> 24) & 255);
#endif
}
__device__ __forceinline__ float4 up4(u32 v) {
    float4 r;
#ifdef HAVE_FP8_CVT
    v2f lo = __builtin_amdgcn_cvt_pk_f32_fp8((int)v, false);
    v2f hi = __builtin_amdgcn_cvt_pk_f32_fp8((int)v, true);
    r.x = lo.x; r.y = lo.y; r.z = hi.x; r.w = hi.y;
#else
    r.x = fp8_to_f32(v & 255);         r.y = fp8_to_f32((v >> 8) & 255);
    r.z = fp8_to_f32((v >> 16) & 255); r.w = fp8_to_f32((v >> 24) & 255);
#endif
    return r;
}
__device__ __forceinline__ u32 pack_fp8x4(float a, float b, float c, float d) {
#ifdef HAVE_FP8_CVT
    int r = __builtin_amdgcn_cvt_pk_fp8_f32(a, b, 0, false);
    r = __builtin_amdgcn_cvt_pk_fp8_f32(c, d, r, true);
    return (u32)r;
#else
    return f32_to_fp8(a) | (f32_to_fp8(b) << 8) | (f32_to_fp8(c) << 16) | (f32_to_fp8(d) << 24);
#endif
}

// ---- gemm: Out(fp8 rows, 64B) = dinv[r] * (X @ W) ----
__global__ void k_gemm_reg(const float* __restrict__ X, const float* __restrict__ W,
                           const float* __restrict__ dinv, u32* __restrict__ Out,
                           int nRows) {
    __shared__ float xs[GR][64];
    int tid = threadIdx.x;
    int lane = tid & 63;
    int wv = tid >> 6;
    float wreg[64];
#pragma unroll
    for (int k = 0; k < 64; ++k) wreg[k] = W[k * 64 + lane];
    for (int t0 = blockIdx.x * GR; t0 < nRows; t0 += gridDim.x * GR) {
        __syncthreads();
        {
            const float4* X4 = (const float4*)(X + (size_t)t0 * 64);
            float4 v0 = X4[tid];
            float4 v1 = X4[tid + 256];
            ((float4*)&xs[0][0])[tid] = v0;
            ((float4*)&xs[0][0])[tid + 256] = v1;
        }
        __syncthreads();
#pragma unroll
        for (int rr = 0; rr < 8; rr += 4) {
            int r = wv * 8 + rr;
            float a0 = 0.f, a1 = 0.f, a2 = 0.f, a3 = 0.f;
#pragma unroll
            for (int k4 = 0; k4 < 16; ++k4) {
                float4 x0 = *(const float4*)&xs[r + 0][k4 * 4];
                float4 x1 = *(const float4*)&xs[r + 1][k4 * 4];
                float4 x2 = *(const float4*)&xs[r + 2][k4 * 4];
                float4 x3 = *(const float4*)&xs[r + 3][k4 * 4];
                a0 = fmaf(x0.x, wreg[k4 * 4 + 0], a0);
                a1 = fmaf(x1.x, wreg[k4 * 4 + 0], a1);
                a2 = fmaf(x2.x, wreg[k4 * 4 + 0], a2);
                a3 = fmaf(x3.x, wreg[k4 * 4 + 0], a3);
                a0 = fmaf(x0.y, wreg[k4 * 4 + 1], a0);
                a1 = fmaf(x1.y, wreg[k4 * 4 + 1], a1);
                a2 = fmaf(x2.y, wreg[k4 * 4 + 1], a2);
                a3 = fmaf(x3.y, wreg[k4 * 4 + 1], a3);
                a0 = fmaf(x0.z, wreg[k4 * 4 + 2], a0);
                a1 = fmaf(x1.z, wreg[k4 * 4 + 2], a1);
                a2 = fmaf(x2.z, wreg[k4 * 4 + 2], a2);
                a3 = fmaf(x3.z, wreg[k4 * 4 + 2], a3);
                a0 = fmaf(x0.w, wreg[k4 * 4 + 3], a0);
                a1 = fmaf(x1.w, wreg[k4 * 4 + 3], a1);
                a2 = fmaf(x2.w, wreg[k4 * 4 + 3], a2);
                a3 = fmaf(x3.w, wreg[k4 * 4 + 3], a3);
            }
            a0 *= dinv[t0 + r + 0];
            a1 *= dinv[t0 + r + 1];
            a2 *= dinv[t0 + r + 2];
            a3 *= dinv[t0 + r + 3];
            float a0_1 = __shfl_xor(a0, 1), a0_2 = __shfl_xor(a0, 2), a0_3 = __shfl_xor(a0, 3);
            float a1_1 = __shfl_xor(a1, 1), a1_2 = __shfl_xor(a1, 2), a1_3 = __shfl_xor(a1, 3);
            float a2_1 = __shfl_xor(a2, 1), a2_2 = __shfl_xor(a2, 2), a2_3 = __shfl_xor(a2, 3);
            float a3_1 = __shfl_xor(a3, 1), a3_2 = __shfl_xor(a3, 2), a3_3 = __shfl_xor(a3, 3);
            if (!(lane & 3)) {
                int h = lane >> 2;
                Out[(size_t)(t0 + r + 0) * 16 + h] = pack_fp8x4(a0, a0_1, a0_2, a0_3);
                Out[(size_t)(t0 + r + 1) * 16 + h] = pack_fp8x4(a1, a1_1, a1_2, a1_3);
                Out[(size_t)(t0 + r + 2) * 16 + h] = pack_fp8x4(a2, a2_1, a2_2, a2_3);
                Out[(size_t)(t0 + r + 3) * 16 + h] = pack_fp8x4(a3, a3_1, a3_2, a3_3);
            }
        }
    }
}

// ---- pass 1a: LDS histogram over dst>>8; block 0 zeroes gsum ----
__global__ void k_hist(const int* __restrict__ dst, int* __restrict__ histT,
                       float* __restrict__ zbuf, int nZ, int nE, int NBUCK) {
    __shared__ int h[512];
    int tid = threadIdx.x;
    if (blockIdx.x == 0) {
        for (int i = tid; i < nZ; i += 256) zbuf[i] = 0.f;
    }
    for (int k = tid; k < NBUCK; k += 256) h[k] = 0;
    __syncthreads();
    int i = blockIdx.x * 256 + tid, stride = NB1 * 256;
    for (; i < nE; i += stride) atomicAdd(&h[dst[i] >> 8], 1);
    __syncthreads();
    for (int k = tid; k < NBUCK; k += 256) histT[k * NB1 + blockIdx.x] = h[k];
}

// ---- scan stage A ----
__global__ void k_scanA(const int* __restrict__ arr, int* __restrict__ outp,
                        int* __restrict__ bsums, int L) {
    __shared__ int sh[SCAN_T];
    int b = blockIdx.x, tid = threadIdx.x;
    int base = b * SCAN_B + tid * SCAN_E;
    int v[SCAN_E];
    int s = 0;
#pragma unroll
    for (int j = 0; j < SCAN_E; ++j) {
        int idx = base + j;
        int c = (idx < L) ? arr[idx] : 0;
        v[j] = s;
        s += c;
    }
    sh[tid] = s;
    __syncthreads();
    for (int off = 1; off < SCAN_T; off <<= 1) {
        int t = (tid >= off) ? sh[tid - off] : 0;
        __syncthreads();
        sh[tid] += t;
        __syncthreads();
    }
    int excl = (tid == 0) ? 0 : sh[tid - 1];
    if (tid == SCAN_T - 1) bsums[b] = sh[tid];
#pragma unroll
    for (int j = 0; j < SCAN_E; ++j) {
        int idx = base + j;
        if (idx < L) outp[idx] = excl + v[j];
    }
}

// ---- scan stage B + folds (serial scan, Wc/bc fold, bsearch gcnt) ----
__global__ void k_scanB_fold(int* __restrict__ bsums, int nB,
                             const float* __restrict__ W2, const float* __restrict__ b2,
                             const float* __restrict__ Wl, const float* __restrict__ bl,
                             float* __restrict__ Wc, float* __restrict__ bc,
                             const int* __restrict__ batch, float* __restrict__ gcnt,
                             int nN) {
    int tid = threadIdx.x;
    if (tid == 0) {
        int run = 0;
        for (int i = 0; i < nB; ++i) {
            int t = bsums[i];
            bsums[i] = run;
            run += t;
        }
    } else if (tid >= 64 && tid < 64 + 192) {
        int i = tid - 64;
        int k = i / 3, j = i % 3;
        float acc = 0.f;
#pragma unroll
        for (int c = 0; c < 64; ++c) acc = fmaf(W2[k * 64 + c], Wl[c * 3 + j], acc);
        Wc[k * 3 + j] = acc;
    } else if (tid >= 1 && tid <= 3) {
        int j = tid - 1;
        float acc = bl[j];
#pragma unroll
        for (int c = 0; c < 64; ++c) acc = fmaf(b2[c], Wl[c * 3 + j], acc);
        bc[j] = acc;
    } else if (tid >= 256 && tid < 256 + NGRAPH) {
        int g = tid - 256;
        int lo = 0, hi = nN;
        while (lo < hi) { int mid = (lo + hi) >> 1; if (batch[mid] < g) lo = mid + 1; else hi = mid; }
        int lb = lo;
        lo = 0; hi = nN;
        int g1 = g + 1;
        while (lo < hi) { int mid = (lo + hi) >> 1; if (batch[mid] < g1) lo = mid + 1; else hi = mid; }
        gcnt[g] = (float)(lo - lb);
    }
}

// ---- pass 1c: partition edges into buckets via LDS cursors ----
__global__ void k_partition(const int* __restrict__ src, const int* __restrict__ dst,
                            const int* __restrict__ scanned, const int* __restrict__ bsums,
                            u32* __restrict__ staged, int nE, int NBUCK) {
    __shared__ int cur[512];
    int tid = threadIdx.x;
    for (int k = tid; k < NBUCK; k += 256) {
        int idx = k * NB1 + blockIdx.x;
        cur[k] = scanned[idx] + bsums[idx >> 12];
    }
    __syncthreads();
    int i = blockIdx.x * 256 + tid, stride = NB1 * 256;
    for (; i < nE; i += stride) {
        int d = dst[i];
        int k = d >> 8;
        int pos = atomicAdd(&cur[k], 1);
        staged[pos] = (u32)src[i] | ((u32)(d & 255) << 20);
    }
}

// ---- pass 2: per-bucket LDS count+scan+place -> esrc, rowptr, dinv ----
__global__ void k_pass2(const u32* __restrict__ staged, const int* __restrict__ scanned,
                        const int* __restrict__ bsums,
                        float* __restrict__ dinv, int* __restrict__ rowptr,
                        int* __restrict__ esrc, int nN, int nE, int NBUCK) {
    __shared__ int cnt[256], cur[256], sh[256];
    int bk = blockIdx.x, tid = threadIdx.x;
    int i0 = bk * NB1;
    int base = scanned[i0] + bsums[i0 >> 12];
    int end = nE;
    if (bk + 1 < NBUCK) {
        int i1 = (bk + 1) * NB1;
        end = scanned[i1] + bsums[i1 >> 12];
    }
    cnt[tid] = 0;
    __syncthreads();
    for (int e = base + tid; e < end; e += 256) atomicAdd(&cnt[staged[e] >> 20], 1);
    __syncthreads();
    int v = cnt[tid];
    sh[tid] = v;
    __syncthreads();
    for (int off = 1; off < 256; off <<= 1) {
        int t = (tid >= off) ? sh[tid - off] : 0;
        __syncthreads();
        sh[tid] += t;
        __syncthreads();
    }
    int excl = sh[tid] - v;
    int node = bk * 256 + tid;
    if (node < nN) {
        rowptr[node] = base + excl;
        dinv[node] = rsqrtf(1.0f + (float)v);
    }
    cur[tid] = excl;
    __syncthreads();
    for (int e = base + tid; e < end; e += 256) {
        u32 r = staged[e];
        int j = r >> 20;
        int pos = atomicAdd(&cur[j], 1);
        esrc[base + pos] = (int)(r & 0xFFFFFu);
    }
    if (bk == 0 && tid == 0) rowptr[nN] = nE;
}

// ---- 8-wide fp8 edge accumulation ----
#define GACC8(H, lane, ep, acc) { \
    int s0 = (ep)[0], s1 = (ep)[1], s2 = (ep)[2], s3 = (ep)[3]; \
    int s4 = (ep)[4], s5 = (ep)[5], s6 = (ep)[6], s7 = (ep)[7]; \
    u32 v0 = H[(size_t)s0 * 16 + lane]; u32 v1 = H[(size_t)s1 * 16 + lane]; \
    u32 v2 = H[(size_t)s2 * 16 + lane]; u32 v3 = H[(size_t)s3 * 16 + lane]; \
    u32 v4 = H[(size_t)s4 * 16 + lane]; u32 v5 = H[(size_t)s5 * 16 + lane]; \
    u32 v6 = H[(size_t)s6 * 16 + lane]; u32 v7 = H[(size_t)s7 * 16 + lane]; \
    up_add(v0, acc); up_add(v1, acc); up_add(v2, acc); up_add(v3, acc); \
    up_add(v4, acc); up_add(v5, acc); up_add(v6, acc); up_add(v7, acc); }

// ---- layer-1 gather (fp8 in, fp8 out): ys1 = dinv*relu(dinv*(sum+self)+b) ----
__global__ void k_gather1(const int* __restrict__ rowptr, const int* __restrict__ esrc,
                          const u32* __restrict__ H, const float* __restrict__ dinv,
                          const float* __restrict__ bias, u32* __restrict__ Of8,
                          int nN) {
    int node = blockIdx.x * 16 + (threadIdx.x >> 4);
    int lane = threadIdx.x & 15;
    if (node >= nN) return;
    int e0 = rowptr[node], e1 = rowptr[node + 1];
    float4 acc = make_float4(0.f, 0.f, 0.f, 0.f);
    int e = e0;
    for (; e + 7 < e1; e += 8) GACC8(H, lane, (esrc + e), acc)
    for (; e < e1; ++e) up_add(H[(size_t)esrc[e] * 16 + lane], acc);
    float di = dinv[node];
    float4 hv = up4(H[(size_t)node * 16 + lane]);
    float4 bb = ((const float4*)bias)[lane];
    float x0 = di * (acc.x + hv.x) + bb.x;
    float x1 = di * (acc.y + hv.y) + bb.y;
    float x2 = di * (acc.z + hv.z) + bb.z;
    float x3 = di * (acc.w + hv.w) + bb.w;
    x0 = fmaxf(x0, 0.f); x1 = fmaxf(x1, 0.f);
    x2 = fmaxf(x2, 0.f); x3 = fmaxf(x3, 0.f);
    Of8[(size_t)node * 16 + lane] = pack_fp8x4(di * x0, di * x1, di * x2, di * x3);
}

// ---- layer-2 gather (fp8 in, bf16 out): z = dinv*(sum+self) ----
__global__ void k_gather2(const int* __restrict__ rowptr, const int* __restrict__ esrc,
                          const u32* __restrict__ H, const float* __restrict__ dinv,
                          uint2* __restrict__ Obf, int nN) {
    int node = blockIdx.x * 16 + (threadIdx.x >> 4);
    int lane = threadIdx.x & 15;
    if (node >= nN) return;
    int e0 = rowptr[node], e1 = rowptr[node + 1];
    float4 acc = make_float4(0.f, 0.f, 0.f, 0.f);
    int e = e0;
    for (; e + 7 < e1; e += 8) GACC8(H, lane, (esrc + e), acc)
    for (; e < e1; ++e) up_add(H[(size_t)esrc[e] * 16 + lane], acc);
    float di = dinv[node];
    float4 hv = up4(H[(size_t)node * 16 + lane]);
    float x0 = di * (acc.x + hv.x);
    float x1 = di * (acc.y + hv.y);
    float x2 = di * (acc.z + hv.z);
    float x3 = di * (acc.w + hv.w);
    Obf[(size_t)node * 16 + lane] = make_uint2(packbf(x0, x1), packbf(x2, x3));
}

// ---- pool (bf16 Z): CH=64 nodes/block; uniform-chunk fast path ----
__global__ void k_pool(const u32* __restrict__ Z32, const int* __restrict__ batch,
                       float* __restrict__ gsum, int nN) {
    const int CH = 64;
    __shared__ int bsh[CH];
    __shared__ float red[4][64];
    int n0 = blockIdx.x * CH;
    int tid = threadIdx.x;
    int f = tid & 63, rl = tid >> 6;
    int nend = n0 + CH; if (nend > nN) nend = nN;
    int cnt = nend - n0;
    if (cnt <= 0) return;
    if (tid < CH) bsh[tid] = (n0 + tid < nN) ? batch[n0 + tid] : -1;
    __syncthreads();
    int g0 = bsh[0];
    bool uniform = (cnt == CH) && (bsh[CH - 1] == g0);
    int col = f >> 1, half = f & 1;
    if (uniform) {
        const u32* Zp = Z32 + (size_t)n0 * 32 + col;
        float acc = 0.f;
#pragma unroll
        for (int r = 0; r < 16; ++r) {
            u32 v = Zp[(size_t)(rl + r * 4) * 32];
            acc += half ? bfhi(v) : bflo(v);
        }
        red[rl][f] = acc;
        __syncthreads();
        if (rl == 0) {
            float s = red[0][f] + red[1][f] + red[2][f] + red[3][f];
            unsafeAtomicAdd(&gsum[g0 * 64 + f], s);
        }
    } else {
        int curg = -1; float acc = 0.f;
        for (int n = n0 + rl; n < nend; n += 4) {
            int g = bsh[n - n0];
            if (g != curg) {
                if (curg >= 0) unsafeAtomicAdd(&gsum[curg * 64 + f], acc);
                curg = g; acc = 0.f;
            }
            u32 v = Z32[(size_t)n * 32 + col];
            acc += half ? bfhi(v) : bflo(v);
        }
        if (curg >= 0) unsafeAtomicAdd(&gsum[curg * 64 + f], acc);
    }
}

// ---- head: out[g] = softmax( mean_g @ Wc + bc ) ----
__global__ void k_head(const float* __restrict__ gsum, const float* __restrict__ gcnt,
                       const float* __restrict__ Wc, const float* __restrict__ bc,
                       float* __restrict__ out) {
    int g = threadIdx.x;
    if (g >= NGRAPH) return;
    float inv = 1.0f / fmaxf(gcnt[g], 1.0f);
    float l0 = bc[0], l1 = bc[1], l2 = bc[2];
#pragma unroll
    for (int k = 0; k < 64; ++k) {
        float m = gsum[g * 64 + k] * inv;
        l0 = fmaf(m, Wc[k * 3 + 0], l0);
        l1 = fmaf(m, Wc[k * 3 + 1], l1);
        l2 = fmaf(m, Wc[k * 3 + 2], l2);
    }
    float mx = fmaxf(l0, fmaxf(l1, l2));
    float e0 = expf(l0 - mx), e1 = expf(l1 - mx), e2 = expf(l2 - mx);
    float s = e0 + e1 + e2;
    out[g * 3 + 0] = e0 / s;
    out[g * 3 + 1] = e1 / s;
    out[g * 3 + 2] = e2 / s;
}

extern "C" void kernel_launch(void* const* d_in, const int* in_sizes, int n_in,
                              void* d_out, int out_size, void* d_ws, size_t ws_size,
                              hipStream_t stream) {
    const float* x     = (const float*)d_in[0];
    const int*   ei    = (const int*)d_in[1];
    const int*   batch = (const int*)d_in[2];
    const float* W1    = (const float*)d_in[3];
    const float* b1    = (const float*)d_in[4];
    const float* W2    = (const float*)d_in[5];
    const float* b2    = (const float*)d_in[6];
    const float* Wl    = (const float*)d_in[7];
    const float* bl    = (const float*)d_in[8];
    float* out = (float*)d_out;

    int nN = in_sizes[2];
    int nE = in_sizes[1] / 2;
    const int* srcp = ei;
    const int* dstp = ei + nE;

    int NBUCK = (nN + 255) >> 8;
    int L = NBUCK * NB1;
    int nB = (L + SCAN_B - 1) / SCAN_B;

    char* ws = (char*)d_ws;
    size_t off = 0;
    auto alloc = [&](size_t bytes) -> void* {
        void* p = ws + off;
        off += (bytes + 255) & ~(size_t)255;
        return p;
    };
    float* dinv    = (float*)alloc((size_t)nN * 4);
    int*   rowptr  = (int*)alloc(((size_t)nN + 1) * 4);
    int*   hist    = (int*)alloc((size_t)L * 4);
    int*   scanned = (int*)alloc((size_t)L * 4);
    int*   bsums   = (int*)alloc(256 * 4);
    u32*   staged  = (u32*)alloc((size_t)nE * 4);
    int*   esrc    = (int*)alloc((size_t)nE * 4);
    u32*   Hf8     = (u32*)alloc((size_t)nN * 16 * 4);   // fp8 rows [nN][64], 64B
    u32*   Yf8     = (u32*)alloc((size_t)nN * 16 * 4);
    u32*   Zbf     = (u32*)alloc((size_t)nN * 32 * 4);   // bf16 rows for pool
    float* gsum    = (float*)alloc(NGRAPH * 64 * 4);
    float* gcnt    = (float*)alloc(NGRAPH * 4);
    float* Wc      = (float*)alloc(64 * 3 * 4);
    float* bc      = (float*)alloc(3 * 4);

    // atomic-free CSR (block 0 zeroes gsum; gcnt set in scanB via bsearch)
    k_hist<<<NB1, 256, 0, stream>>>(dstp, hist, gsum, NGRAPH * 64, nE, NBUCK);
    k_scanA<<<nB, SCAN_T, 0, stream>>>(hist, scanned, bsums, L);
    k_scanB_fold<<<1, 512, 0, stream>>>(bsums, nB, W2, b2, Wl, bl, Wc, bc,
                                        batch, gcnt, nN);
    k_partition<<<NB1, 256, 0, stream>>>(srcp, dstp, scanned, bsums, staged, nE, NBUCK);
    k_pass2<<<NBUCK, 256, 0, stream>>>(staged, scanned, bsums, dinv, rowptr, esrc, nN, nE, NBUCK);

    // hs = dinv * (x@W1), fp8 rows
    k_gemm_reg<<<1024, 256, 0, stream>>>(x, W1, dinv, Hf8, nN);

    // layer 1: ys1 = dinv * relu(gather(hs)+b1) -> Yf8
    k_gather1<<<(nN + 15) / 16, 256, 0, stream>>>(rowptr, esrc, Hf8, dinv, b1, Yf8, nN);
    // layer 2: z = dinv*(gather(ys1)+self) -> Zbf
    k_gather2<<<(nN + 15) / 16, 256, 0, stream>>>(rowptr, esrc, Yf8, dinv, (uint2*)Zbf, nN);

    // pool Zbf + folded head
    k_pool<<<(nN + 63) / 64, 256, 0, stream>>>(Zbf, batch, gsum, nN);
    k_head<<<1, 64, 0, stream>>>(gsum, gcnt, Wc, bc, out);
}

// Round 14
// 137.257 us; speedup vs baseline: 1.9060x; 1.1325x over previous
//
#include <hip/hip_runtime.h>

// GridGNN: 2x GCNConv(64->64) + ReLU, global_mean_pool, Linear(64->3), softmax.
// N=100000 nodes, E=1600000 edges, G=64 graphs, F=64 feats.
// R1 CSR+gather 454 | R4 radix CSR + bf16 rows 235 | R5 reg-GEMM 199
// R6 pool+prescale 177 | R7 memset fold 172 | R8-R10 fusion detours
// R11 unfused best-of 166 | R12 fp8 rows (64B = 1 line) 155.
// Gathers are latency x MLP bound (VALU 16%, HBM 15%, occ 65%).
// R13: clamped 16-wide unrolled edge blocks in both gathers -- pad past
//      e1 with a zero row at index nN (adds exact 0.0): 16 unconditional
//      independent line loads per iteration (2x in-flight), no serial tail,
//      trip count ceil(deg/16) (mostly 1-2). Bitwise-identical math.

typedef unsigned int u32;
typedef float v2f __attribute__((ext_vector_type(2)));

#define NGRAPH 64
#define SCAN_T 256
#define SCAN_E 16
#define SCAN_B 4096
#define NB1 256
#define GR 32

#if __has_builtin(__builtin_amdgcn_cvt_pk_f32_fp8) && __has_builtin(__builtin_amdgcn_cvt_pk_fp8_f32)
#define HAVE_FP8_CVT 1
#endif

// ---- bf16 helpers ----
__device__ __forceinline__ float bflo(u32 v) { return __uint_as_float(v << 16); }
__device__ __forceinline__ float bfhi(u32 v) { return __uint_as_float(v & 0xffff0000u); }
__device__ __forceinline__ u32 packbf(float a, float b) {
    u32 ua = __float_as_uint(a); ua += 0x7fff + ((ua >> 16) & 1);
    u32 ub = __float_as_uint(b); ub += 0x7fff + ((ub >> 16) & 1);
    return (ua >> 16) | ((ub >> 16) << 16);
}

// ---- fp8 e4m3 (OCP) helpers ----
#ifndef HAVE_FP8_CVT
__device__ __forceinline__ float fp8_to_f32(u32 b) {
    u32 s = b & 0x80;
    u32 em = b & 0x7f;
    float fn = __uint_as_float((em << 20) + 0x3C000000u);
    float fs = (float)(b & 7) * 0.001953125f;
    float f = (em & 0x78) ? fn : fs;
    return s ? -f : f;
}
__device__ __forceinline__ u32 f32_to_fp8(float f) {
    u32 u = __float_as_uint(f);
    u32 s = (u >> 24) & 0x80;
    u32 a = u & 0x7fffffff;
    float af = __uint_as_float(a);
    if (af < 0.015625f) {
        u32 m = (u32)__float2int_rn(af * 512.0f);
        if (m >= 8) return s | 0x08;
        return s | m;
    }
    u32 r = a + 0x0007FFFFu + ((a >> 20) & 1);
    int em = (int)(r >> 20) - (120 << 3);
    if (em > 0x7E) em = 0x7E;
    if (em < 0) em = 0;
    return s | (u32)em;
}
#endif

__device__ __forceinline__ void up_add(u32 v, float4& acc) {
#ifdef HAVE_FP8_CVT
    v2f lo = __builtin_amdgcn_cvt_pk_f32_fp8((int)v, false);
    v2f hi = __builtin_amdgcn_cvt_pk_f32_fp8((int)v, true);
    acc.x += lo.x; acc.y += lo.y; acc.z += hi.x; acc.w += hi.y;
#else
    acc.x += fp8_to_f32(v & 255);         acc.y += fp8_to_f32((v >> 8) & 255);
    acc.z += fp8_to_f32((v >> 16) & 255); acc.w += fp8_to_f32((v >> 24) & 255);
#endif
}
__device__ __forceinline__ float4 up4(u32 v) {
    float4 r;
#ifdef HAVE_FP8_CVT
    v2f lo = __builtin_amdgcn_cvt_pk_f32_fp8((int)v, false);
    v2f hi = __builtin_amdgcn_cvt_pk_f32_fp8((int)v, true);
    r.x = lo.x; r.y = lo.y; r.z = hi.x; r.w = hi.y;
#else
    r.x = fp8_to_f32(v & 255);         r.y = fp8_to_f32((v >> 8) & 255);
    r.z = fp8_to_f32((v >> 16) & 255); r.w = fp8_to_f32((v >> 24) & 255);
#endif
    return r;
}
__device__ __forceinline__ u32 pack_fp8x4(float a, float b, float c, float d) {
#ifdef HAVE_FP8_CVT
    int r = __builtin_amdgcn_cvt_pk_fp8_f32(a, b, 0, false);
    r = __builtin_amdgcn_cvt_pk_fp8_f32(c, d, r, true);
    return (u32)r;
#else
    return f32_to_fp8(a) | (f32_to_fp8(b) << 8) | (f32_to_fp8(c) << 16) | (f32_to_fp8(d) << 24);
#endif
}

// ---- gemm: Out(fp8 rows, 64B) = dinv[r] * (X @ W) ----
__global__ void k_gemm_reg(const float* __restrict__ X, const float* __restrict__ W,
                           const float* __restrict__ dinv, u32* __restrict__ Out,
                           int nRows) {
    __shared__ float xs[GR][64];
    int tid = threadIdx.x;
    int lane = tid & 63;
    int wv = tid >> 6;
    float wreg[64];
#pragma unroll
    for (int k = 0; k < 64; ++k) wreg[k] = W[k * 64 + lane];
    for (int t0 = blockIdx.x * GR; t0 < nRows; t0 += gridDim.x * GR) {
        __syncthreads();
        {
            const float4* X4 = (const float4*)(X + (size_t)t0 * 64);
            float4 v0 = X4[tid];
            float4 v1 = X4[tid + 256];
            ((float4*)&xs[0][0])[tid] = v0;
            ((float4*)&xs[0][0])[tid + 256] = v1;
        }
        __syncthreads();
#pragma unroll
        for (int rr = 0; rr < 8; rr += 4) {
            int r = wv * 8 + rr;
            float a0 = 0.f, a1 = 0.f, a2 = 0.f, a3 = 0.f;
#pragma unroll
            for (int k4 = 0; k4 < 16; ++k4) {
                float4 x0 = *(const float4*)&xs[r + 0][k4 * 4];
                float4 x1 = *(const float4*)&xs[r + 1][k4 * 4];
                float4 x2 = *(const float4*)&xs[r + 2][k4 * 4];
                float4 x3 = *(const float4*)&xs[r + 3][k4 * 4];
                a0 = fmaf(x0.x, wreg[k4 * 4 + 0], a0);
                a1 = fmaf(x1.x, wreg[k4 * 4 + 0], a1);
                a2 = fmaf(x2.x, wreg[k4 * 4 + 0], a2);
                a3 = fmaf(x3.x, wreg[k4 * 4 + 0], a3);
                a0 = fmaf(x0.y, wreg[k4 * 4 + 1], a0);
                a1 = fmaf(x1.y, wreg[k4 * 4 + 1], a1);
                a2 = fmaf(x2.y, wreg[k4 * 4 + 1], a2);
                a3 = fmaf(x3.y, wreg[k4 * 4 + 1], a3);
                a0 = fmaf(x0.z, wreg[k4 * 4 + 2], a0);
                a1 = fmaf(x1.z, wreg[k4 * 4 + 2], a1);
                a2 = fmaf(x2.z, wreg[k4 * 4 + 2], a2);
                a3 = fmaf(x3.z, wreg[k4 * 4 + 2], a3);
                a0 = fmaf(x0.w, wreg[k4 * 4 + 3], a0);
                a1 = fmaf(x1.w, wreg[k4 * 4 + 3], a1);
                a2 = fmaf(x2.w, wreg[k4 * 4 + 3], a2);
                a3 = fmaf(x3.w, wreg[k4 * 4 + 3], a3);
            }
            a0 *= dinv[t0 + r + 0];
            a1 *= dinv[t0 + r + 1];
            a2 *= dinv[t0 + r + 2];
            a3 *= dinv[t0 + r + 3];
            float a0_1 = __shfl_xor(a0, 1), a0_2 = __shfl_xor(a0, 2), a0_3 = __shfl_xor(a0, 3);
            float a1_1 = __shfl_xor(a1, 1), a1_2 = __shfl_xor(a1, 2), a1_3 = __shfl_xor(a1, 3);
            float a2_1 = __shfl_xor(a2, 1), a2_2 = __shfl_xor(a2, 2), a2_3 = __shfl_xor(a2, 3);
            float a3_1 = __shfl_xor(a3, 1), a3_2 = __shfl_xor(a3, 2), a3_3 = __shfl_xor(a3, 3);
            if (!(lane & 3)) {
                int h = lane >> 2;
                Out[(size_t)(t0 + r + 0) * 16 + h] = pack_fp8x4(a0, a0_1, a0_2, a0_3);
                Out[(size_t)(t0 + r + 1) * 16 + h] = pack_fp8x4(a1, a1_1, a1_2, a1_3);
                Out[(size_t)(t0 + r + 2) * 16 + h] = pack_fp8x4(a2, a2_1, a2_2, a2_3);
                Out[(size_t)(t0 + r + 3) * 16 + h] = pack_fp8x4(a3, a3_1, a3_2, a3_3);
            }
        }
    }
}

// ---- pass 1a: LDS histogram over dst>>8; block 0 zeroes gsum + zero-rows ----
__global__ void k_hist(const int* __restrict__ dst, int* __restrict__ histT,
                       float* __restrict__ zbuf, int nZ,
                       u32* __restrict__ Hz, u32* __restrict__ Yz,
                       int nE, int NBUCK) {
    __shared__ int h[512];
    int tid = threadIdx.x;
    if (blockIdx.x == 0) {
        for (int i = tid; i < nZ; i += 256) zbuf[i] = 0.f;
        if (tid < 16) { Hz[tid] = 0u; Yz[tid] = 0u; }  // zero row at index nN
    }
    for (int k = tid; k < NBUCK; k += 256) h[k] = 0;
    __syncthreads();
    int i = blockIdx.x * 256 + tid, stride = NB1 * 256;
    for (; i < nE; i += stride) atomicAdd(&h[dst[i] >> 8], 1);
    __syncthreads();
    for (int k = tid; k < NBUCK; k += 256) histT[k * NB1 + blockIdx.x] = h[k];
}

// ---- scan stage A ----
__global__ void k_scanA(const int* __restrict__ arr, int* __restrict__ outp,
                        int* __restrict__ bsums, int L) {
    __shared__ int sh[SCAN_T];
    int b = blockIdx.x, tid = threadIdx.x;
    int base = b * SCAN_B + tid * SCAN_E;
    int v[SCAN_E];
    int s = 0;
#pragma unroll
    for (int j = 0; j < SCAN_E; ++j) {
        int idx = base + j;
        int c = (idx < L) ? arr[idx] : 0;
        v[j] = s;
        s += c;
    }
    sh[tid] = s;
    __syncthreads();
    for (int off = 1; off < SCAN_T; off <<= 1) {
        int t = (tid >= off) ? sh[tid - off] : 0;
        __syncthreads();
        sh[tid] += t;
        __syncthreads();
    }
    int excl = (tid == 0) ? 0 : sh[tid - 1];
    if (tid == SCAN_T - 1) bsums[b] = sh[tid];
#pragma unroll
    for (int j = 0; j < SCAN_E; ++j) {
        int idx = base + j;
        if (idx < L) outp[idx] = excl + v[j];
    }
}

// ---- scan stage B + folds (serial scan, Wc/bc fold, bsearch gcnt) ----
__global__ void k_scanB_fold(int* __restrict__ bsums, int nB,
                             const float* __restrict__ W2, const float* __restrict__ b2,
                             const float* __restrict__ Wl, const float* __restrict__ bl,
                             float* __restrict__ Wc, float* __restrict__ bc,
                             const int* __restrict__ batch, float* __restrict__ gcnt,
                             int nN) {
    int tid = threadIdx.x;
    if (tid == 0) {
        int run = 0;
        for (int i = 0; i < nB; ++i) {
            int t = bsums[i];
            bsums[i] = run;
            run += t;
        }
    } else if (tid >= 64 && tid < 64 + 192) {
        int i = tid - 64;
        int k = i / 3, j = i % 3;
        float acc = 0.f;
#pragma unroll
        for (int c = 0; c < 64; ++c) acc = fmaf(W2[k * 64 + c], Wl[c * 3 + j], acc);
        Wc[k * 3 + j] = acc;
    } else if (tid >= 1 && tid <= 3) {
        int j = tid - 1;
        float acc = bl[j];
#pragma unroll
        for (int c = 0; c < 64; ++c) acc = fmaf(b2[c], Wl[c * 3 + j], acc);
        bc[j] = acc;
    } else if (tid >= 256 && tid < 256 + NGRAPH) {
        int g = tid - 256;
        int lo = 0, hi = nN;
        while (lo < hi) { int mid = (lo + hi) >> 1; if (batch[mid] < g) lo = mid + 1; else hi = mid; }
        int lb = lo;
        lo = 0; hi = nN;
        int g1 = g + 1;
        while (lo < hi) { int mid = (lo + hi) >> 1; if (batch[mid] < g1) lo = mid + 1; else hi = mid; }
        gcnt[g] = (float)(lo - lb);
    }
}

// ---- pass 1c: partition edges into buckets via LDS cursors ----
__global__ void k_partition(const int* __restrict__ src, const int* __restrict__ dst,
                            const int* __restrict__ scanned, const int* __restrict__ bsums,
                            u32* __restrict__ staged, int nE, int NBUCK) {
    __shared__ int cur[512];
    int tid = threadIdx.x;
    for (int k = tid; k < NBUCK; k += 256) {
        int idx = k * NB1 + blockIdx.x;
        cur[k] = scanned[idx] + bsums[idx >> 12];
    }
    __syncthreads();
    int i = blockIdx.x * 256 + tid, stride = NB1 * 256;
    for (; i < nE; i += stride) {
        int d = dst[i];
        int k = d >> 8;
        int pos = atomicAdd(&cur[k], 1);
        staged[pos] = (u32)src[i] | ((u32)(d & 255) << 20);
    }
}

// ---- pass 2: per-bucket LDS count+scan+place -> esrc, rowptr, dinv ----
__global__ void k_pass2(const u32* __restrict__ staged, const int* __restrict__ scanned,
                        const int* __restrict__ bsums,
                        float* __restrict__ dinv, int* __restrict__ rowptr,
                        int* __restrict__ esrc, int nN, int nE, int NBUCK) {
    __shared__ int cnt[256], cur[256], sh[256];
    int bk = blockIdx.x, tid = threadIdx.x;
    int i0 = bk * NB1;
    int base = scanned[i0] + bsums[i0 >> 12];
    int end = nE;
    if (bk + 1 < NBUCK) {
        int i1 = (bk + 1) * NB1;
        end = scanned[i1] + bsums[i1 >> 12];
    }
    cnt[tid] = 0;
    __syncthreads();
    for (int e = base + tid; e < end; e += 256) atomicAdd(&cnt[staged[e] >> 20], 1);
    __syncthreads();
    int v = cnt[tid];
    sh[tid] = v;
    __syncthreads();
    for (int off = 1; off < 256; off <<= 1) {
        int t = (tid >= off) ? sh[tid - off] : 0;
        __syncthreads();
        sh[tid] += t;
        __syncthreads();
    }
    int excl = sh[tid] - v;
    int node = bk * 256 + tid;
    if (node < nN) {
        rowptr[node] = base + excl;
        dinv[node] = rsqrtf(1.0f + (float)v);
    }
    cur[tid] = excl;
    __syncthreads();
    for (int e = base + tid; e < end; e += 256) {
        u32 r = staged[e];
        int j = r >> 20;
        int pos = atomicAdd(&cur[j], 1);
        esrc[base + pos] = (int)(r & 0xFFFFFu);
    }
    if (bk == 0 && tid == 0) rowptr[nN] = nE;
}

// ---- clamped 16-wide edge block: indices past e1 -> zero row (adds 0.0) ----
#define GACC16C(H, lane, esrc, b, e1, zrow, acc) { \
    int i0 = (b)+0  < (e1) ? (esrc)[(b)+0]  : (zrow); \
    int i1 = (b)+1  < (e1) ? (esrc)[(b)+1]  : (zrow); \
    int i2 = (b)+2  < (e1) ? (esrc)[(b)+2]  : (zrow); \
    int i3 = (b)+3  < (e1) ? (esrc)[(b)+3]  : (zrow); \
    int i4 = (b)+4  < (e1) ? (esrc)[(b)+4]  : (zrow); \
    int i5 = (b)+5  < (e1) ? (esrc)[(b)+5]  : (zrow); \
    int i6 = (b)+6  < (e1) ? (esrc)[(b)+6]  : (zrow); \
    int i7 = (b)+7  < (e1) ? (esrc)[(b)+7]  : (zrow); \
    int i8 = (b)+8  < (e1) ? (esrc)[(b)+8]  : (zrow); \
    int i9 = (b)+9  < (e1) ? (esrc)[(b)+9]  : (zrow); \
    int iA = (b)+10 < (e1) ? (esrc)[(b)+10] : (zrow); \
    int iB = (b)+11 < (e1) ? (esrc)[(b)+11] : (zrow); \
    int iC = (b)+12 < (e1) ? (esrc)[(b)+12] : (zrow); \
    int iD = (b)+13 < (e1) ? (esrc)[(b)+13] : (zrow); \
    int iE = (b)+14 < (e1) ? (esrc)[(b)+14] : (zrow); \
    int iF = (b)+15 < (e1) ? (esrc)[(b)+15] : (zrow); \
    u32 v0 = H[(size_t)i0 * 16 + lane]; u32 v1 = H[(size_t)i1 * 16 + lane]; \
    u32 v2 = H[(size_t)i2 * 16 + lane]; u32 v3 = H[(size_t)i3 * 16 + lane]; \
    u32 v4 = H[(size_t)i4 * 16 + lane]; u32 v5 = H[(size_t)i5 * 16 + lane]; \
    u32 v6 = H[(size_t)i6 * 16 + lane]; u32 v7 = H[(size_t)i7 * 16 + lane]; \
    u32 v8 = H[(size_t)i8 * 16 + lane]; u32 v9 = H[(size_t)i9 * 16 + lane]; \
    u32 vA = H[(size_t)iA * 16 + lane]; u32 vB = H[(size_t)iB * 16 + lane]; \
    u32 vC = H[(size_t)iC * 16 + lane]; u32 vD = H[(size_t)iD * 16 + lane]; \
    u32 vE = H[(size_t)iE * 16 + lane]; u32 vF = H[(size_t)iF * 16 + lane]; \
    up_add(v0, acc); up_add(v1, acc); up_add(v2, acc); up_add(v3, acc); \
    up_add(v4, acc); up_add(v5, acc); up_add(v6, acc); up_add(v7, acc); \
    up_add(v8, acc); up_add(v9, acc); up_add(vA, acc); up_add(vB, acc); \
    up_add(vC, acc); up_add(vD, acc); up_add(vE, acc); up_add(vF, acc); }

// ---- layer-1 gather (fp8 in, fp8 out): ys1 = dinv*relu(dinv*(sum+self)+b) ----
__global__ void k_gather1(const int* __restrict__ rowptr, const int* __restrict__ esrc,
                          const u32* __restrict__ H, const float* __restrict__ dinv,
                          const float* __restrict__ bias, u32* __restrict__ Of8,
                          int nN) {
    int node = blockIdx.x * 16 + (threadIdx.x >> 4);
    int lane = threadIdx.x & 15;
    if (node >= nN) return;
    int e0 = rowptr[node], e1 = rowptr[node + 1];
    float4 acc = make_float4(0.f, 0.f, 0.f, 0.f);
    for (int b = e0; b < e1; b += 16) GACC16C(H, lane, esrc, b, e1, nN, acc)
    float di = dinv[node];
    float4 hv = up4(H[(size_t)node * 16 + lane]);
    float4 bb = ((const float4*)bias)[lane];
    float x0 = di * (acc.x + hv.x) + bb.x;
    float x1 = di * (acc.y + hv.y) + bb.y;
    float x2 = di * (acc.z + hv.z) + bb.z;
    float x3 = di * (acc.w + hv.w) + bb.w;
    x0 = fmaxf(x0, 0.f); x1 = fmaxf(x1, 0.f);
    x2 = fmaxf(x2, 0.f); x3 = fmaxf(x3, 0.f);
    Of8[(size_t)node * 16 + lane] = pack_fp8x4(di * x0, di * x1, di * x2, di * x3);
}

// ---- layer-2 gather (fp8 in, bf16 out): z = dinv*(sum+self) ----
__global__ void k_gather2(const int* __restrict__ rowptr, const int* __restrict__ esrc,
                          const u32* __restrict__ H, const float* __restrict__ dinv,
                          uint2* __restrict__ Obf, int nN) {
    int node = blockIdx.x * 16 + (threadIdx.x >> 4);
    int lane = threadIdx.x & 15;
    if (node >= nN) return;
    int e0 = rowptr[node], e1 = rowptr[node + 1];
    float4 acc = make_float4(0.f, 0.f, 0.f, 0.f);
    for (int b = e0; b < e1; b += 16) GACC16C(H, lane, esrc, b, e1, nN, acc)
    float di = dinv[node];
    float4 hv = up4(H[(size_t)node * 16 + lane]);
    float x0 = di * (acc.x + hv.x);
    float x1 = di * (acc.y + hv.y);
    float x2 = di * (acc.z + hv.z);
    float x3 = di * (acc.w + hv.w);
    Obf[(size_t)node * 16 + lane] = make_uint2(packbf(x0, x1), packbf(x2, x3));
}

// ---- pool (bf16 Z): CH=64 nodes/block; uniform-chunk fast path ----
__global__ void k_pool(const u32* __restrict__ Z32, const int* __restrict__ batch,
                       float* __restrict__ gsum, int nN) {
    const int CH = 64;
    __shared__ int bsh[CH];
    __shared__ float red[4][64];
    int n0 = blockIdx.x * CH;
    int tid = threadIdx.x;
    int f = tid & 63, rl = tid >> 6;
    int nend = n0 + CH; if (nend > nN) nend = nN;
    int cnt = nend - n0;
    if (cnt <= 0) return;
    if (tid < CH) bsh[tid] = (n0 + tid < nN) ? batch[n0 + tid] : -1;
    __syncthreads();
    int g0 = bsh[0];
    bool uniform = (cnt == CH) && (bsh[CH - 1] == g0);
    int col = f >> 1, half = f & 1;
    if (uniform) {
        const u32* Zp = Z32 + (size_t)n0 * 32 + col;
        float acc = 0.f;
#pragma unroll
        for (int r = 0; r < 16; ++r) {
            u32 v = Zp[(size_t)(rl + r * 4) * 32];
            acc += half ? bfhi(v) : bflo(v);
        }
        red[rl][f] = acc;
        __syncthreads();
        if (rl == 0) {
            float s = red[0][f] + red[1][f] + red[2][f] + red[3][f];
            unsafeAtomicAdd(&gsum[g0 * 64 + f], s);
        }
    } else {
        int curg = -1; float acc = 0.f;
        for (int n = n0 + rl; n < nend; n += 4) {
            int g = bsh[n - n0];
            if (g != curg) {
                if (curg >= 0) unsafeAtomicAdd(&gsum[curg * 64 + f], acc);
                curg = g; acc = 0.f;
            }
            u32 v = Z32[(size_t)n * 32 + col];
            acc += half ? bfhi(v) : bflo(v);
        }
        if (curg >= 0) unsafeAtomicAdd(&gsum[curg * 64 + f], acc);
    }
}

// ---- head: out[g] = softmax( mean_g @ Wc + bc ) ----
__global__ void k_head(const float* __restrict__ gsum, const float* __restrict__ gcnt,
                       const float* __restrict__ Wc, const float* __restrict__ bc,
                       float* __restrict__ out) {
    int g = threadIdx.x;
    if (g >= NGRAPH) return;
    float inv = 1.0f / fmaxf(gcnt[g], 1.0f);
    float l0 = bc[0], l1 = bc[1], l2 = bc[2];
#pragma unroll
    for (int k = 0; k < 64; ++k) {
        float m = gsum[g * 64 + k] * inv;
        l0 = fmaf(m, Wc[k * 3 + 0], l0);
        l1 = fmaf(m, Wc[k * 3 + 1], l1);
        l2 = fmaf(m, Wc[k * 3 + 2], l2);
    }
    float mx = fmaxf(l0, fmaxf(l1, l2));
    float e0 = expf(l0 - mx), e1 = expf(l1 - mx), e2 = expf(l2 - mx);
    float s = e0 + e1 + e2;
    out[g * 3 + 0] = e0 / s;
    out[g * 3 + 1] = e1 / s;
    out[g * 3 + 2] = e2 / s;
}

extern "C" void kernel_launch(void* const* d_in, const int* in_sizes, int n_in,
                              void* d_out, int out_size, void* d_ws, size_t ws_size,
                              hipStream_t stream) {
    const float* x     = (const float*)d_in[0];
    const int*   ei    = (const int*)d_in[1];
    const int*   batch = (const int*)d_in[2];
    const float* W1    = (const float*)d_in[3];
    const float* b1    = (const float*)d_in[4];
    const float* W2    = (const float*)d_in[5];
    const float* b2    = (const float*)d_in[6];
    const float* Wl    = (const float*)d_in[7];
    const float* bl    = (const float*)d_in[8];
    float* out = (float*)d_out;

    int nN = in_sizes[2];
    int nE = in_sizes[1] / 2;
    const int* srcp = ei;
    const int* dstp = ei + nE;

    int NBUCK = (nN + 255) >> 8;
    int L = NBUCK * NB1;
    int nB = (L + SCAN_B - 1) / SCAN_B;

    char* ws = (char*)d_ws;
    size_t off = 0;
    auto alloc = [&](size_t bytes) -> void* {
        void* p = ws + off;
        off += (bytes + 255) & ~(size_t)255;
        return p;
    };
    float* dinv    = (float*)alloc((size_t)nN * 4);
    int*   rowptr  = (int*)alloc(((size_t)nN + 1) * 4);
    int*   hist    = (int*)alloc((size_t)L * 4);
    int*   scanned = (int*)alloc((size_t)L * 4);
    int*   bsums   = (int*)alloc(256 * 4);
    u32*   staged  = (u32*)alloc((size_t)nE * 4);
    int*   esrc    = (int*)alloc(((size_t)nE + 16) * 4);   // +16 slack for clamped reads
    u32*   Hf8     = (u32*)alloc(((size_t)nN + 1) * 16 * 4); // +1 zero row at index nN
    u32*   Yf8     = (u32*)alloc(((size_t)nN + 1) * 16 * 4);
    u32*   Zbf     = (u32*)alloc((size_t)nN * 32 * 4);
    float* gsum    = (float*)alloc(NGRAPH * 64 * 4);
    float* gcnt    = (float*)alloc(NGRAPH * 4);
    float* Wc      = (float*)alloc(64 * 3 * 4);
    float* bc      = (float*)alloc(3 * 4);

    // atomic-free CSR (block 0 zeroes gsum + the two zero rows)
    k_hist<<<NB1, 256, 0, stream>>>(dstp, hist, gsum, NGRAPH * 64,
                                    Hf8 + (size_t)nN * 16, Yf8 + (size_t)nN * 16,
                                    nE, NBUCK);
    k_scanA<<<nB, SCAN_T, 0, stream>>>(hist, scanned, bsums, L);
    k_scanB_fold<<<1, 512, 0, stream>>>(bsums, nB, W2, b2, Wl, bl, Wc, bc,
                                        batch, gcnt, nN);
    k_partition<<<NB1, 256, 0, stream>>>(srcp, dstp, scanned, bsums, staged, nE, NBUCK);
    k_pass2<<<NBUCK, 256, 0, stream>>>(staged, scanned, bsums, dinv, rowptr, esrc, nN, nE, NBUCK);

    // hs = dinv * (x@W1), fp8 rows
    k_gemm_reg<<<1024, 256, 0, stream>>>(x, W1, dinv, Hf8, nN);

    // layer 1: ys1 = dinv * relu(gather(hs)+b1) -> Yf8
    k_gather1<<<(nN + 15) / 16, 256, 0, stream>>>(rowptr, esrc, Hf8, dinv, b1, Yf8, nN);
    // layer 2: z = dinv*(gather(ys1)+self) -> Zbf
    k_gather2<<<(nN + 15) / 16, 256, 0, stream>>>(rowptr, esrc, Yf8, dinv, (uint2*)Zbf, nN);

    // pool Zbf + folded head
    k_pool<<<(nN + 63) / 64, 256, 0, stream>>>(Zbf, batch, gsum, nN);
    k_head<<<1, 64, 0, stream>>>(gsum, gcnt, Wc, bc, out);
}